// Round 2
// baseline (6349.220 us; speedup 1.0000x reference)
//
#include <hip/hip_runtime.h>

typedef unsigned int u32;
typedef unsigned short u16;

#define N_NODES 150000
#define E_EDGES 300000

__device__ __forceinline__ float blo(u32 u){ return __uint_as_float(u << 16); }
__device__ __forceinline__ float bhi(u32 u){ return __uint_as_float(u & 0xffff0000u); }
__device__ __forceinline__ float b2f(u16 h){ return __uint_as_float(((u32)h) << 16); }
__device__ __forceinline__ u16 f2bf(float f){
  u32 u = __float_as_uint(f);
  u32 r = (u + 0x7fffu + ((u >> 16) & 1u)) >> 16;   // RNE
  return (u16)r;
}
__device__ __forceinline__ u32 pack2(float a, float b){
  return (u32)f2bf(a) | ((u32)f2bf(b) << 16);
}
// order-preserving float->uint key for atomicMax-based segment max
__device__ __forceinline__ u32 fkey(float f){
  u32 u = __float_as_uint(f);
  return (u & 0x80000000u) ? ~u : (u | 0x80000000u);
}
__device__ __forceinline__ float unkey(u32 k){
  u32 u = (k & 0x80000000u) ? (k ^ 0x80000000u) : ~u32(k);
  return __uint_as_float(u);
}

// C0/C1[M,128](bf16) = A[M,128] @ {B0,B1}; blockIdx.y picks B/C.
template<int ABF16>
__global__ __launch_bounds__(256)
void gemm_qs(const void* __restrict__ Aall, const float* __restrict__ B0,
             const float* __restrict__ B1, u16* __restrict__ C0,
             u16* __restrict__ C1, int M)
{
  __shared__ u16 As[16384];   // [k=128][r=128]
  __shared__ u16 Bs[16384];   // [k=128][c=128]
  const float* B = blockIdx.y ? B1 : B0;
  u16* C = blockIdx.y ? C1 : C0;
  const int t = threadIdx.x;
  const int row0 = blockIdx.x * 128;
  const int c4 = (t & 31) << 2;
  const int g = t >> 5;

  #pragma unroll
  for (int i = 0; i < 16; ++i) {
    int r = i * 8 + g;
    if (ABF16) {
      ushort4 v = make_ushort4(0, 0, 0, 0);
      if (row0 + r < M)
        v = *(const ushort4*)((const u16*)Aall + (size_t)(row0 + r) * 128 + c4);
      As[(c4 + 0) * 128 + r] = v.x;
      As[(c4 + 1) * 128 + r] = v.y;
      As[(c4 + 2) * 128 + r] = v.z;
      As[(c4 + 3) * 128 + r] = v.w;
    } else {
      float4 v = make_float4(0.f, 0.f, 0.f, 0.f);
      if (row0 + r < M)
        v = *(const float4*)((const float*)Aall + (size_t)(row0 + r) * 128 + c4);
      As[(c4 + 0) * 128 + r] = f2bf(v.x);
      As[(c4 + 1) * 128 + r] = f2bf(v.y);
      As[(c4 + 2) * 128 + r] = f2bf(v.z);
      As[(c4 + 3) * 128 + r] = f2bf(v.w);
    }
    float4 w = *(const float4*)(B + r * 128 + c4);
    *(u32*)(Bs + r * 128 + c4)     = pack2(w.x, w.y);
    *(u32*)(Bs + r * 128 + c4 + 2) = pack2(w.z, w.w);
  }
  __syncthreads();

  const int c0 = (t & 15) * 8;
  const int r0 = (t >> 4) * 8;
  float acc[8][8];
  #pragma unroll
  for (int i = 0; i < 8; ++i)
    #pragma unroll
    for (int j = 0; j < 8; ++j) acc[i][j] = 0.f;

  #pragma unroll 4
  for (int k = 0; k < 128; ++k) {
    uint4 av = *(const uint4*)(As + (k << 7) + r0);
    uint4 bv = *(const uint4*)(Bs + (k << 7) + c0);
    float a[8] = { blo(av.x), bhi(av.x), blo(av.y), bhi(av.y),
                   blo(av.z), bhi(av.z), blo(av.w), bhi(av.w) };
    float b[8] = { blo(bv.x), bhi(bv.x), blo(bv.y), bhi(bv.y),
                   blo(bv.z), bhi(bv.z), blo(bv.w), bhi(bv.w) };
    #pragma unroll
    for (int i = 0; i < 8; ++i)
      #pragma unroll
      for (int j = 0; j < 8; ++j) acc[i][j] = fmaf(a[i], b[j], acc[i][j]);
  }

  #pragma unroll
  for (int i = 0; i < 8; ++i) {
    int row = row0 + r0 + i;
    if (row < M) {
      uint4 w;
      w.x = pack2(acc[i][0], acc[i][1]);
      w.y = pack2(acc[i][2], acc[i][3]);
      w.z = pack2(acc[i][4], acc[i][5]);
      w.w = pack2(acc[i][6], acc[i][7]);
      *(uint4*)(C + (size_t)row * 128 + c0) = w;
    }
  }
}

// Fused per-128-edge-tile: edge features -> LDS, tile GEMM vs W (Wk or Wv),
// then SCATTER=0: logits + segment max; SCATTER=1: exp + denom/agg scatter.
template<int XF32, int SCATTER>
__global__ __launch_bounds__(256)
void edge_pass(const void* __restrict__ xg, const float* __restrict__ W,
               const float* __restrict__ Wa, const float* __restrict__ tw,
               const float* __restrict__ tb, const float* __restrict__ dw,
               const float* __restrict__ db, const float* __restrict__ ttab,
               const float* __restrict__ attr, const float* __restrict__ dt,
               const float* __restrict__ dsv, const int* __restrict__ srcA,
               const int* __restrict__ dstA, const int* __restrict__ etA,
               const u16* __restrict__ Q, float* __restrict__ logits,
               u32* __restrict__ mkeys, float* __restrict__ denom,
               float* __restrict__ agg)
{
  __shared__ u16 As[16384];   // kv_in tile, [k=128][e=128]
  __shared__ u16 Bs[16384];   // W tile,     [k=128][c=128]
  const int t = threadIdx.x;
  const int e0 = blockIdx.x * 128;
  const int ne = min(128, E_EDGES - e0);
  const int c4 = (t & 31) << 2;
  const int g = t >> 5;

  // stage W -> Bs (bf16)
  #pragma unroll
  for (int i = 0; i < 16; ++i) {
    int kr = i * 8 + g;
    float4 w = *(const float4*)(W + kr * 128 + c4);
    *(u32*)(Bs + kr * 128 + c4)     = pack2(w.x, w.y);
    *(u32*)(Bs + kr * 128 + c4 + 2) = pack2(w.z, w.w);
  }

  // per-thread-constant columns c4..c4+3
  float4 tw4 = *(const float4*)(tw + c4);
  float4 tb4 = *(const float4*)(tb + c4);
  float4 dw4 = *(const float4*)(dw + c4);
  float4 db4 = *(const float4*)(db + c4);
  float4 wa4[8];
  #pragma unroll
  for (int a = 0; a < 8; ++a) wa4[a] = *(const float4*)(Wa + a * 128 + c4);

  // stage kv_in = x[src] + attr@Wa + cos(dt*tw+tb) + cos(ds*dw+db) + tt[et]
  #pragma unroll
  for (int i = 0; i < 16; ++i) {
    int r = i * 8 + g;
    ushort4 o = make_ushort4(0, 0, 0, 0);
    if (r < ne) {
      int e = e0 + r;
      int src = srcA[e];
      int et = etA[e];
      float dtn = dt[e] * (1.0f / 24.0f);
      float dss = dsv[e];
      float4 tt4 = *(const float4*)(ttab + et * 128 + c4);
      float f0 = __cosf(fmaf(dtn, tw4.x, tb4.x)) + __cosf(fmaf(dss, dw4.x, db4.x)) + tt4.x;
      float f1 = __cosf(fmaf(dtn, tw4.y, tb4.y)) + __cosf(fmaf(dss, dw4.y, db4.y)) + tt4.y;
      float f2 = __cosf(fmaf(dtn, tw4.z, tb4.z)) + __cosf(fmaf(dss, dw4.z, db4.z)) + tt4.z;
      float f3 = __cosf(fmaf(dtn, tw4.w, tb4.w)) + __cosf(fmaf(dss, dw4.w, db4.w)) + tt4.w;
      const float* ap = attr + (size_t)e * 8;
      #pragma unroll
      for (int a = 0; a < 8; ++a) {
        float aa = ap[a];
        f0 = fmaf(aa, wa4[a].x, f0);
        f1 = fmaf(aa, wa4[a].y, f1);
        f2 = fmaf(aa, wa4[a].z, f2);
        f3 = fmaf(aa, wa4[a].w, f3);
      }
      float x0, x1, x2, x3;
      if (XF32) {
        float4 xr = *(const float4*)((const float*)xg + (size_t)src * 128 + c4);
        x0 = xr.x; x1 = xr.y; x2 = xr.z; x3 = xr.w;
      } else {
        ushort4 xr = *(const ushort4*)((const u16*)xg + (size_t)src * 128 + c4);
        x0 = b2f(xr.x); x1 = b2f(xr.y); x2 = b2f(xr.z); x3 = b2f(xr.w);
      }
      o.x = f2bf(x0 + f0);
      o.y = f2bf(x1 + f1);
      o.z = f2bf(x2 + f2);
      o.w = f2bf(x3 + f3);
    }
    As[(c4 + 0) * 128 + r] = o.x;
    As[(c4 + 1) * 128 + r] = o.y;
    As[(c4 + 2) * 128 + r] = o.z;
    As[(c4 + 3) * 128 + r] = o.w;
  }
  __syncthreads();

  const int c0 = (t & 15) * 8;   // dim
  const int r0 = (t >> 4) * 8;   // edge within tile
  float acc[8][8];
  #pragma unroll
  for (int i = 0; i < 8; ++i)
    #pragma unroll
    for (int j = 0; j < 8; ++j) acc[i][j] = 0.f;

  #pragma unroll 4
  for (int k = 0; k < 128; ++k) {
    uint4 av = *(const uint4*)(As + (k << 7) + r0);
    uint4 bv = *(const uint4*)(Bs + (k << 7) + c0);
    float a[8] = { blo(av.x), bhi(av.x), blo(av.y), bhi(av.y),
                   blo(av.z), bhi(av.z), blo(av.w), bhi(av.w) };
    float b[8] = { blo(bv.x), bhi(bv.x), blo(bv.y), bhi(bv.y),
                   blo(bv.z), bhi(bv.z), blo(bv.w), bhi(bv.w) };
    #pragma unroll
    for (int i = 0; i < 8; ++i)
      #pragma unroll
      for (int j = 0; j < 8; ++j) acc[i][j] = fmaf(a[i], b[j], acc[i][j]);
  }

  const int h = (t & 15) >> 2;   // head = c0/32
  #pragma unroll
  for (int i = 0; i < 8; ++i) {
    int r = r0 + i;
    if (r < ne) {                      // uniform across the 4-lane shfl group
      int e = e0 + r;
      int dstn = dstA[e];
      if (SCATTER == 0) {
        uint4 qv = *(const uint4*)(Q + (size_t)dstn * 128 + c0);
        float s = blo(qv.x) * acc[i][0] + bhi(qv.x) * acc[i][1]
                + blo(qv.y) * acc[i][2] + bhi(qv.y) * acc[i][3]
                + blo(qv.z) * acc[i][4] + bhi(qv.z) * acc[i][5]
                + blo(qv.w) * acc[i][6] + bhi(qv.w) * acc[i][7];
        s += __shfl_xor(s, 1, 64);
        s += __shfl_xor(s, 2, 64);
        if ((t & 3) == 0) {
          float lg = s * 0.17677669529663687f;   // 32^-0.5
          lg = (lg >= 0.f) ? lg : 0.2f * lg;     // leaky relu
          logits[(size_t)e * 4 + h] = lg;
          atomicMax(&mkeys[(size_t)dstn * 4 + h], fkey(lg));
        }
      } else {
        float m = unkey(mkeys[(size_t)dstn * 4 + h]);
        float a = __expf(logits[(size_t)e * 4 + h] - m);
        if ((t & 3) == 0) atomicAdd(&denom[(size_t)dstn * 4 + h], a);
        float* ag = agg + (size_t)dstn * 128 + c0;
        #pragma unroll
        for (int j = 0; j < 8; ++j) atomicAdd(ag + j, a * acc[i][j]);
      }
    }
  }
}

// pre = beta*skip + (1-beta)*agg/denom ; accumulate per-column sum/sumsq
__global__ __launch_bounds__(256)
void combine_stats(const float* __restrict__ agg, const float* __restrict__ denom,
                   const u16* __restrict__ S, const float* __restrict__ betaP,
                   float* __restrict__ pre, float* __restrict__ colsum,
                   float* __restrict__ colsumsq)
{
  __shared__ float red[1024];
  const int t = threadIdx.x;
  const int g = t >> 5;
  const int lane = t & 31;
  const int d0 = lane * 4;
  const float beta = *betaP;
  const float omb = 1.f - beta;
  float s4[4] = {0.f, 0.f, 0.f, 0.f};
  float q4[4] = {0.f, 0.f, 0.f, 0.f};
  for (int rep = 0; rep < 16; ++rep) {
    int n = blockIdx.x * 128 + rep * 8 + g;
    if (n < N_NODES) {
      float4 ag = *(const float4*)(agg + (size_t)n * 128 + d0);
      float den = denom[(size_t)n * 4 + (d0 >> 5)];
      float inv = (den > 0.f) ? (1.f / den) : 0.f;   // empty segments -> 0
      ushort4 sv = *(const ushort4*)(S + (size_t)n * 128 + d0);
      float p0 = beta * b2f(sv.x) + omb * ag.x * inv;
      float p1 = beta * b2f(sv.y) + omb * ag.y * inv;
      float p2 = beta * b2f(sv.z) + omb * ag.z * inv;
      float p3 = beta * b2f(sv.w) + omb * ag.w * inv;
      *(float4*)(pre + (size_t)n * 128 + d0) = make_float4(p0, p1, p2, p3);
      s4[0] += p0; s4[1] += p1; s4[2] += p2; s4[3] += p3;
      q4[0] += p0 * p0; q4[1] += p1 * p1; q4[2] += p2 * p2; q4[3] += p3 * p3;
    }
  }
  *(float4*)(&red[g * 128 + d0]) = make_float4(s4[0], s4[1], s4[2], s4[3]);
  __syncthreads();
  if (t < 128) {
    float tot = 0.f;
    #pragma unroll
    for (int gg = 0; gg < 8; ++gg) tot += red[gg * 128 + t];
    atomicAdd(&colsum[t], tot);
  }
  __syncthreads();
  *(float4*)(&red[g * 128 + d0]) = make_float4(q4[0], q4[1], q4[2], q4[3]);
  __syncthreads();
  if (t < 128) {
    float tot = 0.f;
    #pragma unroll
    for (int gg = 0; gg < 8; ++gg) tot += red[gg * 128 + t];
    atomicAdd(&colsumsq[t], tot);
  }
}

// BatchNorm(train stats) + ReLU; LAST: write f32 d_out, else bf16 x-buffer
template<int LAST>
__global__ __launch_bounds__(256)
void bn_apply(const float* __restrict__ pre, const float* __restrict__ colsum,
              const float* __restrict__ colsumsq, const float* __restrict__ gamma,
              const float* __restrict__ bvec, u16* __restrict__ outbf,
              float* __restrict__ outf)
{
  const int idx = blockIdx.x * 256 + threadIdx.x;
  const int n = idx >> 5;
  const int d0 = (idx & 31) * 4;
  const float invN = 1.f / 150000.f;
  float4 p = *(const float4*)(pre + (size_t)n * 128 + d0);
  float4 cs = *(const float4*)(colsum + d0);
  float4 cq = *(const float4*)(colsumsq + d0);
  float4 gm = *(const float4*)(gamma + d0);
  float4 bv = *(const float4*)(bvec + d0);
  float mu, var, y;
  mu = cs.x * invN; var = cq.x * invN - mu * mu;
  y = (p.x - mu) * rsqrtf(var + 1e-5f) * gm.x + bv.x; p.x = fmaxf(y, 0.f);
  mu = cs.y * invN; var = cq.y * invN - mu * mu;
  y = (p.y - mu) * rsqrtf(var + 1e-5f) * gm.y + bv.y; p.y = fmaxf(y, 0.f);
  mu = cs.z * invN; var = cq.z * invN - mu * mu;
  y = (p.z - mu) * rsqrtf(var + 1e-5f) * gm.z + bv.z; p.z = fmaxf(y, 0.f);
  mu = cs.w * invN; var = cq.w * invN - mu * mu;
  y = (p.w - mu) * rsqrtf(var + 1e-5f) * gm.w + bv.w; p.w = fmaxf(y, 0.f);
  if (LAST) {
    *(float4*)(outf + (size_t)n * 128 + d0) = p;
  } else {
    ushort4 o;
    o.x = f2bf(p.x); o.y = f2bf(p.y); o.z = f2bf(p.z); o.w = f2bf(p.w);
    *(ushort4*)(outbf + (size_t)n * 128 + d0) = o;
  }
}

extern "C" void kernel_launch(void* const* d_in, const int* in_sizes, int n_in,
                              void* d_out, int out_size, void* d_ws, size_t ws_size,
                              hipStream_t stream)
{
  const float* x0    = (const float*)d_in[0];
  const float* Wq    = (const float*)d_in[1];
  const float* Wk    = (const float*)d_in[2];
  const float* Wv    = (const float*)d_in[3];
  const float* Wsk   = (const float*)d_in[4];
  const float* Wa    = (const float*)d_in[5];
  const float* tw    = (const float*)d_in[6];
  const float* tb    = (const float*)d_in[7];
  const float* dw    = (const float*)d_in[8];
  const float* db    = (const float*)d_in[9];
  const float* ttab  = (const float*)d_in[10];
  const float* gam   = (const float*)d_in[11];
  const float* bet   = (const float*)d_in[12];
  const float* betaP = (const float*)d_in[13];
  const float* attr  = (const float*)d_in[14];
  const float* dt    = (const float*)d_in[15];
  const float* dsv   = (const float*)d_in[16];
  const int*   eidx  = (const int*)d_in[17];
  const int*   etyp  = (const int*)d_in[18];

  // workspace: 201,601,024 bytes total
  char* p = (char*)d_ws;
  u16* xbf  = (u16*)p;       p += 38400000;   // [N,128] bf16 layer output
  u16* Q    = (u16*)p;       p += 38400000;   // [N,128] bf16
  u16* S    = (u16*)p;       p += 38400000;   // [N,128] bf16
  float* pre = (float*)p;    p += 76800000;   // [N,128] f32
  float* logits = (float*)p; p += 4800000;    // [E,4] f32
  char* zbase = p;                            // contiguous zero block:
  u32* mkeys   = (u32*)p;    p += 2400000;    // [N,4]
  float* denom = (float*)p;  p += 2400000;    // [N,4]
  float* colsum   = (float*)p; p += 512;
  float* colsumsq = (float*)p; p += 512;
  size_t zbytes = (size_t)(p - zbase);

  float* agg = (float*)d_out;   // [N,128] f32 scratch until final bn_apply

  for (int l = 0; l < 4; ++l) {
    const int* srcA = eidx + (size_t)l * 600000;
    const int* dstA = srcA + 300000;
    const float* Wkl = Wk + (size_t)l * 16384;
    const float* Wvl = Wv + (size_t)l * 16384;
    const float* Wal = Wa + (size_t)l * 1024;
    const float* attrl = attr + (size_t)l * 2400000;
    const float* dtl = dt + (size_t)l * 300000;
    const float* dsl = dsv + (size_t)l * 300000;
    const int* etl = etyp + (size_t)l * 300000;

    hipMemsetAsync(zbase, 0, zbytes, stream);
    hipMemsetAsync(agg, 0, 76800000, stream);

    if (l == 0) {
      gemm_qs<0><<<dim3(1172, 2), 256, 0, stream>>>(
          (const void*)x0, Wq, Wsk, Q, S, N_NODES);
      edge_pass<1, 0><<<2344, 256, 0, stream>>>(
          (const void*)x0, Wkl, Wal, tw, tb, dw, db, ttab, attrl, dtl, dsl,
          srcA, dstA, etl, Q, logits, mkeys, denom, agg);
      edge_pass<1, 1><<<2344, 256, 0, stream>>>(
          (const void*)x0, Wvl, Wal, tw, tb, dw, db, ttab, attrl, dtl, dsl,
          srcA, dstA, etl, Q, logits, mkeys, denom, agg);
    } else {
      gemm_qs<1><<<dim3(1172, 2), 256, 0, stream>>>(
          (const void*)xbf, Wq + (size_t)l * 16384, Wsk + (size_t)l * 16384,
          Q, S, N_NODES);
      edge_pass<0, 0><<<2344, 256, 0, stream>>>(
          (const void*)xbf, Wkl, Wal, tw, tb, dw, db, ttab, attrl, dtl, dsl,
          srcA, dstA, etl, Q, logits, mkeys, denom, agg);
      edge_pass<0, 1><<<2344, 256, 0, stream>>>(
          (const void*)xbf, Wvl, Wal, tw, tb, dw, db, ttab, attrl, dtl, dsl,
          srcA, dstA, etl, Q, logits, mkeys, denom, agg);
    }

    combine_stats<<<1172, 256, 0, stream>>>(agg, denom, S, betaP + l,
                                            pre, colsum, colsumsq);

    if (l < 3)
      bn_apply<0><<<18750, 256, 0, stream>>>(pre, colsum, colsumsq,
                                             gam + (size_t)l * 128,
                                             bet + (size_t)l * 128, xbf, nullptr);
    else
      bn_apply<1><<<18750, 256, 0, stream>>>(pre, colsum, colsumsq,
                                             gam + (size_t)l * 128,
                                             bet + (size_t)l * 128,
                                             nullptr, (float*)d_out);
  }
}

// Round 3
// 2771.705 us; speedup vs baseline: 2.2907x; 2.2907x over previous
//
#include <hip/hip_runtime.h>

typedef unsigned int u32;
typedef unsigned short u16;

#define N_NODES 150000
#define E_EDGES 300000
#define L_CNT   151552   // 74*2048, padded per-layer node-count stride

__device__ __forceinline__ float blo(u32 u){ return __uint_as_float(u << 16); }
__device__ __forceinline__ float bhi(u32 u){ return __uint_as_float(u & 0xffff0000u); }
__device__ __forceinline__ float b2f(u16 h){ return __uint_as_float(((u32)h) << 16); }
__device__ __forceinline__ u16 f2bf(float f){
  u32 u = __float_as_uint(f);
  u32 r = (u + 0x7fffu + ((u >> 16) & 1u)) >> 16;   // RNE
  return (u16)r;
}
__device__ __forceinline__ u32 pack2(float a, float b){
  return (u32)f2bf(a) | ((u32)f2bf(b) << 16);
}
// XOR swizzle: store element (dim d, row r) of a [d=128][r=128] u16 tile at
// As[(d<<7) + swz(d,r)]; breaks the 32-way same-bank write conflict (->4-way),
// keeps 8-element (16B) row groups contiguous so uint4 reads still work.
__device__ __forceinline__ int swz(int d, int r){ return r ^ (((d >> 2) & 7) << 3); }

// ---------------- CSR build (counting sort of edges by dst) ----------------

__global__ __launch_bounds__(256)
void k_hist(const int* __restrict__ eidx, int* __restrict__ counts)
{
  const int l = blockIdx.y;
  const int e = blockIdx.x * 256 + threadIdx.x;
  if (e < E_EDGES) {
    int dst = eidx[(size_t)l * 2 * E_EDGES + E_EDGES + e];
    atomicAdd(&counts[(size_t)l * L_CNT + dst], 1);
  }
}

__global__ __launch_bounds__(256)
void k_scan1(const int* __restrict__ counts, int* __restrict__ rowptr,
             int* __restrict__ bsum)
{
  __shared__ int sh[256];
  const int b = blockIdx.x, l = blockIdx.y;
  const int t = threadIdx.x;
  const int* c = counts + (size_t)l * L_CNT + b * 2048;
  int* rp = rowptr + (size_t)l * L_CNT + b * 2048;
  int v[8]; int s = 0;
  #pragma unroll
  for (int j = 0; j < 8; ++j) { v[j] = c[t * 8 + j]; s += v[j]; }
  sh[t] = s; __syncthreads();
  for (int off = 1; off < 256; off <<= 1) {
    int x = (t >= off) ? sh[t - off] : 0;
    __syncthreads();
    sh[t] += x;
    __syncthreads();
  }
  int excl = (t == 0) ? 0 : sh[t - 1];
  if (t == 255) bsum[l * 128 + b] = sh[255];
  int run = excl;
  #pragma unroll
  for (int j = 0; j < 8; ++j) { rp[t * 8 + j] = run; run += v[j]; }
}

__global__ __launch_bounds__(128)
void k_scan2(int* __restrict__ bsum)
{
  __shared__ int sh[128];
  const int l = blockIdx.x, t = threadIdx.x;
  int v = (t < 74) ? bsum[l * 128 + t] : 0;
  sh[t] = v; __syncthreads();
  for (int off = 1; off < 128; off <<= 1) {
    int x = (t >= off) ? sh[t - off] : 0;
    __syncthreads();
    sh[t] += x;
    __syncthreads();
  }
  int excl = (t == 0) ? 0 : sh[t - 1];
  if (t < 74) bsum[l * 128 + t] = excl;
}

__global__ __launch_bounds__(256)
void k_scan3(int* __restrict__ rowptr, int* __restrict__ tmp,
             const int* __restrict__ bsum)
{
  const int l = blockIdx.y;
  const int q = blockIdx.x * 256 + threadIdx.x;   // q < 151552
  int v = rowptr[(size_t)l * L_CNT + q] + bsum[l * 128 + (q >> 11)];
  rowptr[(size_t)l * L_CNT + q] = v;
  tmp[(size_t)l * L_CNT + q] = v;
}

__global__ __launch_bounds__(256)
void k_scatter(const int* __restrict__ eidx, int* __restrict__ tmp,
               int* __restrict__ sorted)
{
  const int l = blockIdx.y;
  const int e = blockIdx.x * 256 + threadIdx.x;
  if (e < E_EDGES) {
    int dst = eidx[(size_t)l * 2 * E_EDGES + E_EDGES + e];
    int pos = atomicAdd(&tmp[(size_t)l * L_CNT + dst], 1);
    sorted[(size_t)l * E_EDGES + pos] = e;
  }
}

// ---------------- node GEMM: Q,S = x @ {Wq, Wskip} ----------------

template<int ABF16>
__global__ __launch_bounds__(256)
void gemm_qs(const void* __restrict__ Aall, const float* __restrict__ B0,
             const float* __restrict__ B1, u16* __restrict__ C0,
             u16* __restrict__ C1, int M)
{
  __shared__ u16 As[16384];   // [k=128][r=128] swizzled
  __shared__ u16 Bs[16384];   // [k=128][c=128]
  const float* B = blockIdx.y ? B1 : B0;
  u16* C = blockIdx.y ? C1 : C0;
  const int t = threadIdx.x;
  const int row0 = blockIdx.x * 128;
  const int c4 = (t & 31) << 2;
  const int g = t >> 5;

  #pragma unroll
  for (int i = 0; i < 16; ++i) {
    int r = i * 8 + g;
    if (ABF16) {
      ushort4 v = make_ushort4(0, 0, 0, 0);
      if (row0 + r < M)
        v = *(const ushort4*)((const u16*)Aall + (size_t)(row0 + r) * 128 + c4);
      As[((c4 + 0) << 7) + swz(c4 + 0, r)] = v.x;
      As[((c4 + 1) << 7) + swz(c4 + 1, r)] = v.y;
      As[((c4 + 2) << 7) + swz(c4 + 2, r)] = v.z;
      As[((c4 + 3) << 7) + swz(c4 + 3, r)] = v.w;
    } else {
      float4 v = make_float4(0.f, 0.f, 0.f, 0.f);
      if (row0 + r < M)
        v = *(const float4*)((const float*)Aall + (size_t)(row0 + r) * 128 + c4);
      As[((c4 + 0) << 7) + swz(c4 + 0, r)] = f2bf(v.x);
      As[((c4 + 1) << 7) + swz(c4 + 1, r)] = f2bf(v.y);
      As[((c4 + 2) << 7) + swz(c4 + 2, r)] = f2bf(v.z);
      As[((c4 + 3) << 7) + swz(c4 + 3, r)] = f2bf(v.w);
    }
    float4 w = *(const float4*)(B + r * 128 + c4);
    *(u32*)(Bs + r * 128 + c4)     = pack2(w.x, w.y);
    *(u32*)(Bs + r * 128 + c4 + 2) = pack2(w.z, w.w);
  }
  __syncthreads();

  const int c0 = (t & 15) * 8;
  const int r0 = (t >> 4) * 8;
  float acc[8][8];
  #pragma unroll
  for (int i = 0; i < 8; ++i)
    #pragma unroll
    for (int j = 0; j < 8; ++j) acc[i][j] = 0.f;

  #pragma unroll 4
  for (int k = 0; k < 128; ++k) {
    uint4 av = *(const uint4*)(As + (k << 7) + swz(k, r0));
    uint4 bv = *(const uint4*)(Bs + (k << 7) + c0);
    float a[8] = { blo(av.x), bhi(av.x), blo(av.y), bhi(av.y),
                   blo(av.z), bhi(av.z), blo(av.w), bhi(av.w) };
    float b[8] = { blo(bv.x), bhi(bv.x), blo(bv.y), bhi(bv.y),
                   blo(bv.z), bhi(bv.z), blo(bv.w), bhi(bv.w) };
    #pragma unroll
    for (int i = 0; i < 8; ++i)
      #pragma unroll
      for (int j = 0; j < 8; ++j) acc[i][j] = fmaf(a[i], b[j], acc[i][j]);
  }

  #pragma unroll
  for (int i = 0; i < 8; ++i) {
    int row = row0 + r0 + i;
    if (row < M) {
      uint4 w;
      w.x = pack2(acc[i][0], acc[i][1]);
      w.y = pack2(acc[i][2], acc[i][3]);
      w.z = pack2(acc[i][4], acc[i][5]);
      w.w = pack2(acc[i][6], acc[i][7]);
      *(uint4*)(C + (size_t)row * 128 + c0) = w;
    }
  }
}

// ---------------- fused edge kernels (dst-sorted order) ----------------
// Per 128-edge sorted tile: build kv_in in LDS, GEMM vs W.
// KPASS=1: dot with Q[dst] -> logits (plain store). KPASS=0: store V rows.
template<int XF32, int KPASS>
__global__ __launch_bounds__(256)
void edge_pass(const void* __restrict__ xg, const float* __restrict__ W,
               const float* __restrict__ Wa, const float* __restrict__ tw,
               const float* __restrict__ tb, const float* __restrict__ dw,
               const float* __restrict__ db, const float* __restrict__ ttab,
               const float* __restrict__ attr, const float* __restrict__ dt,
               const float* __restrict__ dsv, const int* __restrict__ srcA,
               const int* __restrict__ dstA, const int* __restrict__ etA,
               const int* __restrict__ sortedE, const u16* __restrict__ Q,
               float* __restrict__ logits, u16* __restrict__ Vs)
{
  __shared__ u16 As[16384];   // kv_in tile [k=128][e=128] swizzled
  __shared__ u16 Bs[16384];   // W tile     [k=128][c=128]
  const int t = threadIdx.x;
  const int e0 = blockIdx.x * 128;
  const int ne = min(128, E_EDGES - e0);
  const int c4 = (t & 31) << 2;
  const int g = t >> 5;

  #pragma unroll
  for (int i = 0; i < 16; ++i) {
    int kr = i * 8 + g;
    float4 w = *(const float4*)(W + kr * 128 + c4);
    *(u32*)(Bs + kr * 128 + c4)     = pack2(w.x, w.y);
    *(u32*)(Bs + kr * 128 + c4 + 2) = pack2(w.z, w.w);
  }

  float4 tw4 = *(const float4*)(tw + c4);
  float4 tb4 = *(const float4*)(tb + c4);
  float4 dw4 = *(const float4*)(dw + c4);
  float4 db4 = *(const float4*)(db + c4);
  float4 wa4[8];
  #pragma unroll
  for (int a = 0; a < 8; ++a) wa4[a] = *(const float4*)(Wa + a * 128 + c4);

  #pragma unroll
  for (int i = 0; i < 16; ++i) {
    int r = i * 8 + g;
    ushort4 o = make_ushort4(0, 0, 0, 0);
    if (r < ne) {
      int eid = sortedE[e0 + r];
      int src = srcA[eid];
      int et = etA[eid];
      float dtn = dt[eid] * (1.0f / 24.0f);
      float dss = dsv[eid];
      float4 tt4 = *(const float4*)(ttab + et * 128 + c4);
      float f0 = __cosf(fmaf(dtn, tw4.x, tb4.x)) + __cosf(fmaf(dss, dw4.x, db4.x)) + tt4.x;
      float f1 = __cosf(fmaf(dtn, tw4.y, tb4.y)) + __cosf(fmaf(dss, dw4.y, db4.y)) + tt4.y;
      float f2 = __cosf(fmaf(dtn, tw4.z, tb4.z)) + __cosf(fmaf(dss, dw4.z, db4.z)) + tt4.z;
      float f3 = __cosf(fmaf(dtn, tw4.w, tb4.w)) + __cosf(fmaf(dss, dw4.w, db4.w)) + tt4.w;
      const float* ap = attr + (size_t)eid * 8;
      #pragma unroll
      for (int a = 0; a < 8; ++a) {
        float aa = ap[a];
        f0 = fmaf(aa, wa4[a].x, f0);
        f1 = fmaf(aa, wa4[a].y, f1);
        f2 = fmaf(aa, wa4[a].z, f2);
        f3 = fmaf(aa, wa4[a].w, f3);
      }
      float x0, x1, x2, x3;
      if (XF32) {
        float4 xr = *(const float4*)((const float*)xg + (size_t)src * 128 + c4);
        x0 = xr.x; x1 = xr.y; x2 = xr.z; x3 = xr.w;
      } else {
        ushort4 xr = *(const ushort4*)((const u16*)xg + (size_t)src * 128 + c4);
        x0 = b2f(xr.x); x1 = b2f(xr.y); x2 = b2f(xr.z); x3 = b2f(xr.w);
      }
      o.x = f2bf(x0 + f0);
      o.y = f2bf(x1 + f1);
      o.z = f2bf(x2 + f2);
      o.w = f2bf(x3 + f3);
    }
    As[((c4 + 0) << 7) + swz(c4 + 0, r)] = o.x;
    As[((c4 + 1) << 7) + swz(c4 + 1, r)] = o.y;
    As[((c4 + 2) << 7) + swz(c4 + 2, r)] = o.z;
    As[((c4 + 3) << 7) + swz(c4 + 3, r)] = o.w;
  }
  __syncthreads();

  const int c0 = (t & 15) * 8;   // output dim
  const int r0 = (t >> 4) * 8;   // edge within tile
  float acc[8][8];
  #pragma unroll
  for (int i = 0; i < 8; ++i)
    #pragma unroll
    for (int j = 0; j < 8; ++j) acc[i][j] = 0.f;

  #pragma unroll 4
  for (int k = 0; k < 128; ++k) {
    uint4 av = *(const uint4*)(As + (k << 7) + swz(k, r0));
    uint4 bv = *(const uint4*)(Bs + (k << 7) + c0);
    float a[8] = { blo(av.x), bhi(av.x), blo(av.y), bhi(av.y),
                   blo(av.z), bhi(av.z), blo(av.w), bhi(av.w) };
    float b[8] = { blo(bv.x), bhi(bv.x), blo(bv.y), bhi(bv.y),
                   blo(bv.z), bhi(bv.z), blo(bv.w), bhi(bv.w) };
    #pragma unroll
    for (int i = 0; i < 8; ++i)
      #pragma unroll
      for (int j = 0; j < 8; ++j) acc[i][j] = fmaf(a[i], b[j], acc[i][j]);
  }

  if (KPASS) {
    const int h = (t & 15) >> 2;
    #pragma unroll
    for (int i = 0; i < 8; ++i) {
      int r = r0 + i;
      if (r < ne) {                       // uniform across the 4-lane shfl group
        int eid = sortedE[e0 + r];
        int dstn = dstA[eid];
        uint4 qv = *(const uint4*)(Q + (size_t)dstn * 128 + c0);
        float s = blo(qv.x) * acc[i][0] + bhi(qv.x) * acc[i][1]
                + blo(qv.y) * acc[i][2] + bhi(qv.y) * acc[i][3]
                + blo(qv.z) * acc[i][4] + bhi(qv.z) * acc[i][5]
                + blo(qv.w) * acc[i][6] + bhi(qv.w) * acc[i][7];
        s += __shfl_xor(s, 1, 64);
        s += __shfl_xor(s, 2, 64);
        if ((t & 3) == 0) {
          float lg = s * 0.17677669529663687f;   // 32^-0.5
          lg = (lg >= 0.f) ? lg : 0.2f * lg;     // leaky relu
          logits[(size_t)(e0 + r) * 4 + h] = lg;
        }
      }
    }
  } else {
    #pragma unroll
    for (int i = 0; i < 8; ++i) {
      int r = r0 + i;
      if (r < ne) {
        uint4 w;
        w.x = pack2(acc[i][0], acc[i][1]);
        w.y = pack2(acc[i][2], acc[i][3]);
        w.z = pack2(acc[i][4], acc[i][5]);
        w.w = pack2(acc[i][6], acc[i][7]);
        *(uint4*)(Vs + (size_t)(e0 + r) * 128 + c0) = w;
      }
    }
  }
}

// ---------------- per-node softmax + aggregate + combine + stats ----------------
__global__ __launch_bounds__(256)
void node_agg(const u16* __restrict__ Vs, const float* __restrict__ logits,
              const int* __restrict__ rowptr, const u16* __restrict__ S,
              const float* __restrict__ betaP, float* __restrict__ pre,
              float* __restrict__ colsum, float* __restrict__ colsumsq)
{
  __shared__ float red[1024];
  const int t = threadIdx.x;
  const int g = t >> 5;
  const int lane = t & 31;
  const int d0 = lane * 4;
  const int h = lane >> 3;
  const float beta = *betaP;
  const float omb = 1.f - beta;
  float s4[4] = {0.f, 0.f, 0.f, 0.f};
  float q4[4] = {0.f, 0.f, 0.f, 0.f};
  for (int rep = 0; rep < 16; ++rep) {
    int n = blockIdx.x * 128 + rep * 8 + g;
    if (n < N_NODES) {
      int rs = rowptr[n], re = rowptr[n + 1];
      float m = -1e30f;
      for (int i = rs; i < re; ++i)
        m = fmaxf(m, logits[(size_t)i * 4 + h]);
      float den = 0.f;
      float a0 = 0.f, a1 = 0.f, a2 = 0.f, a3 = 0.f;
      for (int i = rs; i < re; ++i) {
        float w = __expf(logits[(size_t)i * 4 + h] - m);
        den += w;
        ushort4 v = *(const ushort4*)(Vs + (size_t)i * 128 + d0);
        a0 = fmaf(w, b2f(v.x), a0);
        a1 = fmaf(w, b2f(v.y), a1);
        a2 = fmaf(w, b2f(v.z), a2);
        a3 = fmaf(w, b2f(v.w), a3);
      }
      float inv = (den > 0.f) ? (omb / den) : 0.f;
      ushort4 sv = *(const ushort4*)(S + (size_t)n * 128 + d0);
      float p0 = fmaf(beta, b2f(sv.x), a0 * inv);
      float p1 = fmaf(beta, b2f(sv.y), a1 * inv);
      float p2 = fmaf(beta, b2f(sv.z), a2 * inv);
      float p3 = fmaf(beta, b2f(sv.w), a3 * inv);
      *(float4*)(pre + (size_t)n * 128 + d0) = make_float4(p0, p1, p2, p3);
      s4[0] += p0; s4[1] += p1; s4[2] += p2; s4[3] += p3;
      q4[0] += p0 * p0; q4[1] += p1 * p1; q4[2] += p2 * p2; q4[3] += p3 * p3;
    }
  }
  *(float4*)(&red[g * 128 + d0]) = make_float4(s4[0], s4[1], s4[2], s4[3]);
  __syncthreads();
  if (t < 128) {
    float tot = 0.f;
    #pragma unroll
    for (int gg = 0; gg < 8; ++gg) tot += red[gg * 128 + t];
    atomicAdd(&colsum[t], tot);
  }
  __syncthreads();
  *(float4*)(&red[g * 128 + d0]) = make_float4(q4[0], q4[1], q4[2], q4[3]);
  __syncthreads();
  if (t < 128) {
    float tot = 0.f;
    #pragma unroll
    for (int gg = 0; gg < 8; ++gg) tot += red[gg * 128 + t];
    atomicAdd(&colsumsq[t], tot);
  }
}

// ---------------- BatchNorm(train stats) + ReLU ----------------
template<int LAST>
__global__ __launch_bounds__(256)
void bn_apply(const float* __restrict__ pre, const float* __restrict__ colsum,
              const float* __restrict__ colsumsq, const float* __restrict__ gamma,
              const float* __restrict__ bvec, u16* __restrict__ outbf,
              float* __restrict__ outf)
{
  const int idx = blockIdx.x * 256 + threadIdx.x;
  const int n = idx >> 5;
  const int d0 = (idx & 31) * 4;
  const float invN = 1.f / 150000.f;
  float4 p = *(const float4*)(pre + (size_t)n * 128 + d0);
  float4 cs = *(const float4*)(colsum + d0);
  float4 cq = *(const float4*)(colsumsq + d0);
  float4 gm = *(const float4*)(gamma + d0);
  float4 bv = *(const float4*)(bvec + d0);
  float mu, var, y;
  mu = cs.x * invN; var = cq.x * invN - mu * mu;
  y = (p.x - mu) * rsqrtf(var + 1e-5f) * gm.x + bv.x; p.x = fmaxf(y, 0.f);
  mu = cs.y * invN; var = cq.y * invN - mu * mu;
  y = (p.y - mu) * rsqrtf(var + 1e-5f) * gm.y + bv.y; p.y = fmaxf(y, 0.f);
  mu = cs.z * invN; var = cq.z * invN - mu * mu;
  y = (p.z - mu) * rsqrtf(var + 1e-5f) * gm.z + bv.z; p.z = fmaxf(y, 0.f);
  mu = cs.w * invN; var = cq.w * invN - mu * mu;
  y = (p.w - mu) * rsqrtf(var + 1e-5f) * gm.w + bv.w; p.w = fmaxf(y, 0.f);
  if (LAST) {
    *(float4*)(outf + (size_t)n * 128 + d0) = p;
  } else {
    ushort4 o;
    o.x = f2bf(p.x); o.y = f2bf(p.y); o.z = f2bf(p.z); o.w = f2bf(p.w);
    *(ushort4*)(outbf + (size_t)n * 128 + d0) = o;
  }
}

extern "C" void kernel_launch(void* const* d_in, const int* in_sizes, int n_in,
                              void* d_out, int out_size, void* d_ws, size_t ws_size,
                              hipStream_t stream)
{
  const float* x0    = (const float*)d_in[0];
  const float* Wq    = (const float*)d_in[1];
  const float* Wk    = (const float*)d_in[2];
  const float* Wv    = (const float*)d_in[3];
  const float* Wsk   = (const float*)d_in[4];
  const float* Wa    = (const float*)d_in[5];
  const float* tw    = (const float*)d_in[6];
  const float* tb    = (const float*)d_in[7];
  const float* dw    = (const float*)d_in[8];
  const float* db    = (const float*)d_in[9];
  const float* ttab  = (const float*)d_in[10];
  const float* gam   = (const float*)d_in[11];
  const float* bet   = (const float*)d_in[12];
  const float* betaP = (const float*)d_in[13];
  const float* attr  = (const float*)d_in[14];
  const float* dt    = (const float*)d_in[15];
  const float* dsv   = (const float*)d_in[16];
  const int*   eidx  = (const int*)d_in[17];
  const int*   etyp  = (const int*)d_in[18];

  // workspace ~206 MB
  char* p = (char*)d_ws;
  u16* xbf  = (u16*)p;       p += 38400000;          // [N,128] bf16
  u16* Q    = (u16*)p;       p += 38400000;          // [N,128] bf16
  u16* S    = (u16*)p;       p += 38400000;          // [N,128] bf16
  u16* Vs   = (u16*)p;       p += 76800000;          // [E,128] bf16, dst-sorted
  float* logits = (float*)p; p += 4800000;           // [E,4] f32, dst-sorted
  int* rowptr = (int*)p;     p += 4 * L_CNT * 4;     // per-layer CSR rowptr
  int* tmp    = (int*)p;     p += 4 * L_CNT * 4;     // scatter cursors (zero-init; also hist counts)
  int* sorted = (int*)p;     p += 4 * E_EDGES * 4;   // per-layer sorted edge ids
  int* bsum   = (int*)p;     p += 4 * 128 * 4;
  float* colsum   = (float*)p; p += 512;
  float* colsumsq = (float*)p; p += 512;

  float* pre = (float*)d_out;   // [N,128] f32 scratch (overwritten in final bn)

  // ---- CSR build for all 4 layers (counts alias tmp) ----
  hipMemsetAsync(tmp, 0, 4 * L_CNT * 4, stream);
  k_hist<<<dim3(1172, 4), 256, 0, stream>>>(eidx, tmp);
  k_scan1<<<dim3(74, 4), 256, 0, stream>>>(tmp, rowptr, bsum);
  k_scan2<<<4, 128, 0, stream>>>(bsum);
  k_scan3<<<dim3(592, 4), 256, 0, stream>>>(rowptr, tmp, bsum);
  k_scatter<<<dim3(1172, 4), 256, 0, stream>>>(eidx, tmp, sorted);

  for (int l = 0; l < 4; ++l) {
    const int* srcA = eidx + (size_t)l * 600000;
    const int* dstA = srcA + 300000;
    const int* sortedE = sorted + (size_t)l * E_EDGES;
    const int* rpl = rowptr + (size_t)l * L_CNT;
    const float* Wkl = Wk + (size_t)l * 16384;
    const float* Wvl = Wv + (size_t)l * 16384;
    const float* Wal = Wa + (size_t)l * 1024;
    const float* attrl = attr + (size_t)l * 2400000;
    const float* dtl = dt + (size_t)l * 300000;
    const float* dsl = dsv + (size_t)l * 300000;
    const int* etl = etyp + (size_t)l * 300000;

    hipMemsetAsync(colsum, 0, 1024, stream);

    if (l == 0) {
      gemm_qs<0><<<dim3(1172, 2), 256, 0, stream>>>(
          (const void*)x0, Wq, Wsk, Q, S, N_NODES);
      edge_pass<1, 1><<<2344, 256, 0, stream>>>(
          (const void*)x0, Wkl, Wal, tw, tb, dw, db, ttab, attrl, dtl, dsl,
          srcA, dstA, etl, sortedE, Q, logits, nullptr);
      edge_pass<1, 0><<<2344, 256, 0, stream>>>(
          (const void*)x0, Wvl, Wal, tw, tb, dw, db, ttab, attrl, dtl, dsl,
          srcA, dstA, etl, sortedE, Q, nullptr, Vs);
    } else {
      gemm_qs<1><<<dim3(1172, 2), 256, 0, stream>>>(
          (const void*)xbf, Wq + (size_t)l * 16384, Wsk + (size_t)l * 16384,
          Q, S, N_NODES);
      edge_pass<0, 1><<<2344, 256, 0, stream>>>(
          (const void*)xbf, Wkl, Wal, tw, tb, dw, db, ttab, attrl, dtl, dsl,
          srcA, dstA, etl, sortedE, Q, logits, nullptr);
      edge_pass<0, 0><<<2344, 256, 0, stream>>>(
          (const void*)xbf, Wvl, Wal, tw, tb, dw, db, ttab, attrl, dtl, dsl,
          srcA, dstA, etl, sortedE, Q, nullptr, Vs);
    }

    node_agg<<<1172, 256, 0, stream>>>(Vs, logits, rpl, S, betaP + l,
                                       pre, colsum, colsumsq);

    if (l < 3)
      bn_apply<0><<<18750, 256, 0, stream>>>(pre, colsum, colsumsq,
                                             gam + (size_t)l * 128,
                                             bet + (size_t)l * 128, xbf, nullptr);
    else
      bn_apply<1><<<18750, 256, 0, stream>>>(pre, colsum, colsumsq,
                                             gam + (size_t)l * 128,
                                             bet + (size_t)l * 128,
                                             nullptr, (float*)d_out);
  }
}

// Round 5
// 2157.048 us; speedup vs baseline: 2.9435x; 1.2850x over previous
//
#include <hip/hip_runtime.h>

typedef unsigned int u32;
typedef unsigned short u16;
typedef short bf16x8 __attribute__((ext_vector_type(8)));
typedef float f32x4 __attribute__((ext_vector_type(4)));

#define N_NODES 150000
#define E_EDGES 300000
#define L_CNT   151552   // 74*2048 padded per-layer node stride

__device__ __forceinline__ float b2f(u16 h){ return __uint_as_float(((u32)h) << 16); }
__device__ __forceinline__ u16 f2bf(float f){
  u32 u = __float_as_uint(f);
  return (u16)((u + 0x7fffu + ((u >> 16) & 1u)) >> 16);   // RNE
}

// Builtin MFMA: compiler models hazards (raw asm corrupted accs in waves that
// hit the barrier last — no NOP insertion). Lax vector conversion bitcasts
// short8 to the builtin's bf16 vector type where needed.
__device__ __forceinline__ f32x4 mfma16(bf16x8 a, bf16x8 b, f32x4 c){
  return __builtin_amdgcn_mfma_f32_16x16x32_bf16(a, b, c, 0, 0, 0);
}

// operand tile [r][128k] u16, XOR-swizzled: conflict-free writes, ~2-way reads
__device__ __forceinline__ int opsw(int r, int k){ return (r * 128 + k) ^ ((r & 7) << 3); }
// C tile [r][128n] u16 swizzle (spreads the 4 row-groups of the MFMA C layout)
__device__ __forceinline__ int csw(int r, int n){ return (r * 128 + n) ^ (((r >> 2) & 3) << 3); }

// ---------------- weight pre-transpose: Wt[n][k] bf16 <- W[k][n] f32 ----------------
__global__ __launch_bounds__(256)
void k_wt(const float* __restrict__ Wq, const float* __restrict__ Wk,
          const float* __restrict__ Wv, const float* __restrict__ Ws,
          u16* __restrict__ Wt)
{
  const int m = blockIdx.x;   // 0..15: [Wq0-3, Wk0-3, Wv0-3, Wsk0-3]
  const float* src = (m < 4 ? Wq : m < 8 ? Wk : m < 12 ? Wv : Ws)
                     + (size_t)(m & 3) * 16384;
  u16* dst = Wt + (size_t)m * 16384;
  const int t = threadIdx.x;
  for (int i = 0; i < 16; ++i) {
    int idx = i * 256 + t;            // 4096 quads
    int n = idx >> 5;
    int k4 = (idx & 31) << 2;
    ushort4 o;
    o.x = f2bf(src[(k4 + 0) * 128 + n]);
    o.y = f2bf(src[(k4 + 1) * 128 + n]);
    o.z = f2bf(src[(k4 + 2) * 128 + n]);
    o.w = f2bf(src[(k4 + 3) * 128 + n]);
    *(ushort4*)(dst + n * 128 + k4) = o;
  }
}

// ---------------- shared device helpers ----------------

__device__ __forceinline__ void stage_w(u16* Bs, const u16* __restrict__ Wt, int t)
{
  #pragma unroll
  for (int i = 0; i < 8; ++i) {
    int cid = i * 256 + t;
    int n = cid >> 4, k8 = (cid & 15) << 3;
    uint4 v = *(const uint4*)(Wt + n * 128 + k8);
    *(uint4*)(Bs + opsw(n, k8)) = v;
  }
}

__device__ __forceinline__ void mfma_tile(const u16* As, const u16* Bs,
                                          f32x4 (&acc)[2][8], int w, int lane)
{
  const int lr = lane & 15;
  const int lk = (lane >> 4) << 3;
  #pragma unroll
  for (int ks = 0; ks < 4; ++ks) {
    const int kb = ks * 32 + lk;
    bf16x8 a0 = *(const bf16x8*)(As + opsw(w * 32 + lr, kb));
    bf16x8 a1 = *(const bf16x8*)(As + opsw(w * 32 + 16 + lr, kb));
    #pragma unroll
    for (int nt = 0; nt < 8; ++nt) {
      bf16x8 b = *(const bf16x8*)(Bs + opsw(nt * 16 + lr, kb));
      acc[0][nt] = mfma16(a0, b, acc[0][nt]);
      acc[1][nt] = mfma16(a1, b, acc[1][nt]);
    }
  }
}

__device__ __forceinline__ void acc_zero(f32x4 (&acc)[2][8])
{
  #pragma unroll
  for (int a = 0; a < 2; ++a)
    #pragma unroll
    for (int b = 0; b < 8; ++b) {
      acc[a][b][0] = 0.f; acc[a][b][1] = 0.f;
      acc[a][b][2] = 0.f; acc[a][b][3] = 0.f;
    }
}

__device__ __forceinline__ void acc_to_lds(u16* Cs, f32x4 (&acc)[2][8], int w, int lane)
{
  const int lr = lane & 15;
  const int g4 = (lane >> 4) << 2;
  #pragma unroll
  for (int mt = 0; mt < 2; ++mt)
    #pragma unroll
    for (int nt = 0; nt < 8; ++nt)
      #pragma unroll
      for (int j = 0; j < 4; ++j)
        Cs[csw(w * 32 + mt * 16 + g4 + j, nt * 16 + lr)] = f2bf(acc[mt][nt][j]);
}

__device__ __forceinline__ void lds_to_global(const u16* Cs, u16* __restrict__ G,
                                              int base, int nr, int t)
{
  #pragma unroll
  for (int i = 0; i < 8; ++i) {
    int cid = i * 256 + t;
    int r = cid >> 4, n8 = (cid & 15) << 3;
    if (r < nr) {
      uint4 v = *(const uint4*)(Cs + csw(r, n8));
      *(uint4*)(G + (size_t)(base + r) * 128 + n8) = v;
    }
  }
}

// ---------------- CSR build (counting sort of edges by dst) ----------------

__global__ __launch_bounds__(256)
void k_hist(const int* __restrict__ eidx, int* __restrict__ counts)
{
  const int l = blockIdx.y;
  const int e = blockIdx.x * 256 + threadIdx.x;
  if (e < E_EDGES) {
    int dst = eidx[(size_t)l * 2 * E_EDGES + E_EDGES + e];
    atomicAdd(&counts[(size_t)l * L_CNT + dst], 1);
  }
}

__global__ __launch_bounds__(256)
void k_scan1(const int* __restrict__ counts, int* __restrict__ rowptr,
             int* __restrict__ bsum)
{
  __shared__ int sh[256];
  const int b = blockIdx.x, l = blockIdx.y;
  const int t = threadIdx.x;
  const int* c = counts + (size_t)l * L_CNT + b * 2048;
  int* rp = rowptr + (size_t)l * L_CNT + b * 2048;
  int v[8]; int s = 0;
  #pragma unroll
  for (int j = 0; j < 8; ++j) { v[j] = c[t * 8 + j]; s += v[j]; }
  sh[t] = s; __syncthreads();
  for (int off = 1; off < 256; off <<= 1) {
    int x = (t >= off) ? sh[t - off] : 0;
    __syncthreads();
    sh[t] += x;
    __syncthreads();
  }
  int excl = (t == 0) ? 0 : sh[t - 1];
  if (t == 255) bsum[l * 128 + b] = sh[255];
  int run = excl;
  #pragma unroll
  for (int j = 0; j < 8; ++j) { rp[t * 8 + j] = run; run += v[j]; }
}

__global__ __launch_bounds__(128)
void k_scan2(int* __restrict__ bsum)
{
  __shared__ int sh[128];
  const int l = blockIdx.x, t = threadIdx.x;
  int v = (t < 74) ? bsum[l * 128 + t] : 0;
  sh[t] = v; __syncthreads();
  for (int off = 1; off < 128; off <<= 1) {
    int x = (t >= off) ? sh[t - off] : 0;
    __syncthreads();
    sh[t] += x;
    __syncthreads();
  }
  int excl = (t == 0) ? 0 : sh[t - 1];
  if (t < 74) bsum[l * 128 + t] = excl;
}

__global__ __launch_bounds__(256)
void k_scan3(int* __restrict__ rowptr, int* __restrict__ tmp,
             const int* __restrict__ bsum)
{
  const int l = blockIdx.y;
  const int q = blockIdx.x * 256 + threadIdx.x;
  int v = rowptr[(size_t)l * L_CNT + q] + bsum[l * 128 + (q >> 11)];
  rowptr[(size_t)l * L_CNT + q] = v;
  tmp[(size_t)l * L_CNT + q] = v;
}

__global__ __launch_bounds__(256)
void k_scatter(const int* __restrict__ eidx, int* __restrict__ tmp,
               int* __restrict__ sorted)
{
  const int l = blockIdx.y;
  const int e = blockIdx.x * 256 + threadIdx.x;
  if (e < E_EDGES) {
    int dst = eidx[(size_t)l * 2 * E_EDGES + E_EDGES + e];
    int pos = atomicAdd(&tmp[(size_t)l * L_CNT + dst], 1);
    sorted[(size_t)l * E_EDGES + pos] = e;
  }
}

// ---------------- node GEMM: Q = x@Wq, S = x@Wskip (MFMA) ----------------

template<int XF32>
__global__ __launch_bounds__(256)
void gemm_qs(const void* __restrict__ xg, const u16* __restrict__ WtQ,
             const u16* __restrict__ WtS, u16* __restrict__ Qo,
             u16* __restrict__ So)
{
  __shared__ __align__(16) u16 As[16384];
  __shared__ __align__(16) u16 Bs[16384];
  const int t = threadIdx.x;
  const int w = t >> 6, lane = t & 63;
  const int row0 = blockIdx.x * 128;
  const int g = t >> 5, c4 = (t & 31) << 2;
  int nr = N_NODES - row0; if (nr > 128) nr = 128;

  // stage x tile -> As [r][k]
  #pragma unroll
  for (int i = 0; i < 16; ++i) {
    int r = i * 8 + g;
    ushort4 o = make_ushort4(0, 0, 0, 0);
    if (r < nr) {
      if (XF32) {
        float4 v = *(const float4*)((const float*)xg + (size_t)(row0 + r) * 128 + c4);
        o.x = f2bf(v.x); o.y = f2bf(v.y); o.z = f2bf(v.z); o.w = f2bf(v.w);
      } else {
        o = *(const ushort4*)((const u16*)xg + (size_t)(row0 + r) * 128 + c4);
      }
    }
    *(ushort4*)(As + opsw(r, c4)) = o;
  }
  stage_w(Bs, WtQ, t);
  __syncthreads();

  f32x4 acc[2][8];
  acc_zero(acc);
  mfma_tile(As, Bs, acc, w, lane);
  __syncthreads();
  acc_to_lds(Bs, acc, w, lane);
  __syncthreads();
  lds_to_global(Bs, Qo, row0, nr, t);
  __syncthreads();

  stage_w(Bs, WtS, t);
  __syncthreads();
  acc_zero(acc);
  mfma_tile(As, Bs, acc, w, lane);
  __syncthreads();
  acc_to_lds(Bs, acc, w, lane);
  __syncthreads();
  lds_to_global(Bs, So, row0, nr, t);
}

// ---------------- fused edge kernel: features -> K-GEMM -> logits -> V-GEMM -> Vs ----------------

template<int XF32>
__global__ __launch_bounds__(256)
void edge_pass(const void* __restrict__ xg, const u16* __restrict__ WtK,
               const u16* __restrict__ WtV, const float* __restrict__ Wa,
               const float* __restrict__ tw, const float* __restrict__ tb,
               const float* __restrict__ dw, const float* __restrict__ db,
               const float* __restrict__ ttab, const float* __restrict__ attr,
               const float* __restrict__ dt, const float* __restrict__ dsv,
               const int* __restrict__ srcA, const int* __restrict__ dstA,
               const int* __restrict__ etA, const int* __restrict__ sortedE,
               const u16* __restrict__ Qb, float* __restrict__ logits,
               u16* __restrict__ Vs)
{
  __shared__ __align__(16) u16 As[16384];
  __shared__ __align__(16) u16 Bs[16384];
  __shared__ int dstSh[128];
  const int t = threadIdx.x;
  const int w = t >> 6, lane = t & 63;
  const int e0 = blockIdx.x * 128;
  const int ne = min(128, E_EDGES - e0);
  const int g = t >> 5, c4 = (t & 31) << 2;

  stage_w(Bs, WtK, t);

  float4 tw4 = *(const float4*)(tw + c4);
  float4 tb4 = *(const float4*)(tb + c4);
  float4 dw4 = *(const float4*)(dw + c4);
  float4 db4 = *(const float4*)(db + c4);
  float4 wa4[8];
  #pragma unroll
  for (int a = 0; a < 8; ++a) wa4[a] = *(const float4*)(Wa + a * 128 + c4);

  // stage kv_in = x[src] + attr@Wa + cos(dt*tw+tb) + cos(ds*dw+db) + tt[et]
  #pragma unroll
  for (int i = 0; i < 16; ++i) {
    int r = i * 8 + g;
    ushort4 o = make_ushort4(0, 0, 0, 0);
    if (r < ne) {
      int eid = sortedE[e0 + r];
      if ((t & 31) == 0) dstSh[r] = dstA[eid];
      int et = etA[eid];
      float dtn = dt[eid] * (1.0f / 24.0f);
      float dss = dsv[eid];
      float4 tt4 = *(const float4*)(ttab + et * 128 + c4);
      float f0 = __cosf(fmaf(dtn, tw4.x, tb4.x)) + __cosf(fmaf(dss, dw4.x, db4.x)) + tt4.x;
      float f1 = __cosf(fmaf(dtn, tw4.y, tb4.y)) + __cosf(fmaf(dss, dw4.y, db4.y)) + tt4.y;
      float f2 = __cosf(fmaf(dtn, tw4.z, tb4.z)) + __cosf(fmaf(dss, dw4.z, db4.z)) + tt4.z;
      float f3 = __cosf(fmaf(dtn, tw4.w, tb4.w)) + __cosf(fmaf(dss, dw4.w, db4.w)) + tt4.w;
      const float* ap = attr + (size_t)eid * 8;
      #pragma unroll
      for (int a = 0; a < 8; ++a) {
        float aa = ap[a];
        f0 = fmaf(aa, wa4[a].x, f0);
        f1 = fmaf(aa, wa4[a].y, f1);
        f2 = fmaf(aa, wa4[a].z, f2);
        f3 = fmaf(aa, wa4[a].w, f3);
      }
      int src = srcA[eid];
      float x0, x1, x2, x3;
      if (XF32) {
        float4 xr = *(const float4*)((const float*)xg + (size_t)src * 128 + c4);
        x0 = xr.x; x1 = xr.y; x2 = xr.z; x3 = xr.w;
      } else {
        ushort4 xr = *(const ushort4*)((const u16*)xg + (size_t)src * 128 + c4);
        x0 = b2f(xr.x); x1 = b2f(xr.y); x2 = b2f(xr.z); x3 = b2f(xr.w);
      }
      o.x = f2bf(x0 + f0);
      o.y = f2bf(x1 + f1);
      o.z = f2bf(x2 + f2);
      o.w = f2bf(x3 + f3);
    }
    *(ushort4*)(As + opsw(r, c4)) = o;
  }
  __syncthreads();

  f32x4 acc[2][8];
  acc_zero(acc);
  mfma_tile(As, Bs, acc, w, lane);   // K = kv @ Wk
  __syncthreads();
  acc_to_lds(Bs, acc, w, lane);      // K rows -> Bs
  __syncthreads();

  // logits: per edge r, per head h: leaky( (Q[dst] . K) * 32^-0.5 )
  #pragma unroll
  for (int i = 0; i < 16; ++i) {
    int r = i * 8 + g;
    if (r < ne) {
      int dstn = dstSh[r];
      ushort4 q = *(const ushort4*)(Qb + (size_t)dstn * 128 + c4);
      ushort4 k = *(const ushort4*)(Bs + csw(r, c4));
      float s = b2f(q.x) * b2f(k.x) + b2f(q.y) * b2f(k.y)
              + b2f(q.z) * b2f(k.z) + b2f(q.w) * b2f(k.w);
      s += __shfl_xor(s, 1, 64);
      s += __shfl_xor(s, 2, 64);
      s += __shfl_xor(s, 4, 64);
      if ((t & 7) == 0) {
        float lg = s * 0.17677669529663687f;     // 32^-0.5
        lg = (lg >= 0.f) ? lg : 0.2f * lg;       // leaky relu
        logits[(size_t)(e0 + r) * 4 + ((t & 31) >> 3)] = lg;
      }
    }
  }
  __syncthreads();

  stage_w(Bs, WtV, t);
  __syncthreads();
  acc_zero(acc);
  mfma_tile(As, Bs, acc, w, lane);   // V = kv @ Wv
  __syncthreads();
  acc_to_lds(Bs, acc, w, lane);
  __syncthreads();
  lds_to_global(Bs, Vs, e0, ne, t);
}

// ---------------- per-node softmax + aggregate + combine + stats ----------------
__global__ __launch_bounds__(256)
void node_agg(const u16* __restrict__ Vs, const float* __restrict__ logits,
              const int* __restrict__ rowptr, const u16* __restrict__ S,
              const float* __restrict__ betaP, float* __restrict__ pre,
              float* __restrict__ colsum, float* __restrict__ colsumsq)
{
  __shared__ float red[1024];
  const int t = threadIdx.x;
  const int g = t >> 5;
  const int lane = t & 31;
  const int d0 = lane * 4;
  const int h = lane >> 3;
  const float beta = *betaP;
  const float omb = 1.f - beta;
  float s4[4] = {0.f, 0.f, 0.f, 0.f};
  float q4[4] = {0.f, 0.f, 0.f, 0.f};
  for (int rep = 0; rep < 16; ++rep) {
    int n = blockIdx.x * 128 + rep * 8 + g;
    if (n < N_NODES) {
      int rs = rowptr[n], re = rowptr[n + 1];
      float m = -1e30f;
      for (int i = rs; i < re; ++i)
        m = fmaxf(m, logits[(size_t)i * 4 + h]);
      float den = 0.f;
      float a0 = 0.f, a1 = 0.f, a2 = 0.f, a3 = 0.f;
      for (int i = rs; i < re; ++i) {
        float wgt = __expf(logits[(size_t)i * 4 + h] - m);
        den += wgt;
        ushort4 v = *(const ushort4*)(Vs + (size_t)i * 128 + d0);
        a0 = fmaf(wgt, b2f(v.x), a0);
        a1 = fmaf(wgt, b2f(v.y), a1);
        a2 = fmaf(wgt, b2f(v.z), a2);
        a3 = fmaf(wgt, b2f(v.w), a3);
      }
      float inv = (den > 0.f) ? (omb / den) : 0.f;
      ushort4 sv = *(const ushort4*)(S + (size_t)n * 128 + d0);
      float p0 = fmaf(beta, b2f(sv.x), a0 * inv);
      float p1 = fmaf(beta, b2f(sv.y), a1 * inv);
      float p2 = fmaf(beta, b2f(sv.z), a2 * inv);
      float p3 = fmaf(beta, b2f(sv.w), a3 * inv);
      *(float4*)(pre + (size_t)n * 128 + d0) = make_float4(p0, p1, p2, p3);
      s4[0] += p0; s4[1] += p1; s4[2] += p2; s4[3] += p3;
      q4[0] += p0 * p0; q4[1] += p1 * p1; q4[2] += p2 * p2; q4[3] += p3 * p3;
    }
  }
  *(float4*)(&red[g * 128 + d0]) = make_float4(s4[0], s4[1], s4[2], s4[3]);
  __syncthreads();
  if (t < 128) {
    float tot = 0.f;
    #pragma unroll
    for (int gg = 0; gg < 8; ++gg) tot += red[gg * 128 + t];
    atomicAdd(&colsum[t], tot);
  }
  __syncthreads();
  *(float4*)(&red[g * 128 + d0]) = make_float4(q4[0], q4[1], q4[2], q4[3]);
  __syncthreads();
  if (t < 128) {
    float tot = 0.f;
    #pragma unroll
    for (int gg = 0; gg < 8; ++gg) tot += red[gg * 128 + t];
    atomicAdd(&colsumsq[t], tot);
  }
}

// ---------------- BatchNorm(train stats) + ReLU ----------------
template<int LAST>
__global__ __launch_bounds__(256)
void bn_apply(const float* __restrict__ pre, const float* __restrict__ colsum,
              const float* __restrict__ colsumsq, const float* __restrict__ gamma,
              const float* __restrict__ bvec, u16* __restrict__ outbf,
              float* __restrict__ outf)
{
  const int idx = blockIdx.x * 256 + threadIdx.x;
  const int n = idx >> 5;
  const int d0 = (idx & 31) * 4;
  const float invN = 1.f / 150000.f;
  float4 p = *(const float4*)(pre + (size_t)n * 128 + d0);
  float4 cs = *(const float4*)(colsum + d0);
  float4 cq = *(const float4*)(colsumsq + d0);
  float4 gm = *(const float4*)(gamma + d0);
  float4 bv = *(const float4*)(bvec + d0);
  float mu, var, y;
  mu = cs.x * invN; var = cq.x * invN - mu * mu;
  y = (p.x - mu) * rsqrtf(var + 1e-5f) * gm.x + bv.x; p.x = fmaxf(y, 0.f);
  mu = cs.y * invN; var = cq.y * invN - mu * mu;
  y = (p.y - mu) * rsqrtf(var + 1e-5f) * gm.y + bv.y; p.y = fmaxf(y, 0.f);
  mu = cs.z * invN; var = cq.z * invN - mu * mu;
  y = (p.z - mu) * rsqrtf(var + 1e-5f) * gm.z + bv.z; p.z = fmaxf(y, 0.f);
  mu = cs.w * invN; var = cq.w * invN - mu * mu;
  y = (p.w - mu) * rsqrtf(var + 1e-5f) * gm.w + bv.w; p.w = fmaxf(y, 0.f);
  if (LAST) {
    *(float4*)(outf + (size_t)n * 128 + d0) = p;
  } else {
    ushort4 o;
    o.x = f2bf(p.x); o.y = f2bf(p.y); o.z = f2bf(p.z); o.w = f2bf(p.w);
    *(ushort4*)(outbf + (size_t)n * 128 + d0) = o;
  }
}

extern "C" void kernel_launch(void* const* d_in, const int* in_sizes, int n_in,
                              void* d_out, int out_size, void* d_ws, size_t ws_size,
                              hipStream_t stream)
{
  const float* x0    = (const float*)d_in[0];
  const float* Wq    = (const float*)d_in[1];
  const float* Wk    = (const float*)d_in[2];
  const float* Wv    = (const float*)d_in[3];
  const float* Wsk   = (const float*)d_in[4];
  const float* Wa    = (const float*)d_in[5];
  const float* tw    = (const float*)d_in[6];
  const float* tb    = (const float*)d_in[7];
  const float* dw    = (const float*)d_in[8];
  const float* db    = (const float*)d_in[9];
  const float* ttab  = (const float*)d_in[10];
  const float* gam   = (const float*)d_in[11];
  const float* bet   = (const float*)d_in[12];
  const float* betaP = (const float*)d_in[13];
  const float* attr  = (const float*)d_in[14];
  const float* dt    = (const float*)d_in[15];
  const float* dsv   = (const float*)d_in[16];
  const int*   eidx  = (const int*)d_in[17];
  const int*   etyp  = (const int*)d_in[18];

  // workspace ~207 MB
  char* p = (char*)d_ws;
  u16* xbf  = (u16*)p;       p += 38400000;          // [N,128] bf16
  u16* Q    = (u16*)p;       p += 38400000;          // [N,128] bf16
  u16* S    = (u16*)p;       p += 38400000;          // [N,128] bf16
  u16* Vs   = (u16*)p;       p += 76800000;          // [E,128] bf16 dst-sorted
  float* logits = (float*)p; p += 4800000;           // [E,4] f32 dst-sorted
  int* rowptr = (int*)p;     p += 4 * L_CNT * 4;
  int* tmp    = (int*)p;     p += 4 * L_CNT * 4;
  int* sorted = (int*)p;     p += 4 * E_EDGES * 4;
  int* bsum   = (int*)p;     p += 4 * 128 * 4;
  float* colsum   = (float*)p; p += 512;
  float* colsumsq = (float*)p; p += 512;
  u16* Wt = (u16*)p;         p += 16 * 16384 * 2;    // 16 transposed bf16 weights

  float* pre = (float*)d_out;   // [N,128] f32 scratch (final bn overwrites)

  // weight transpose + CSR build
  k_wt<<<16, 256, 0, stream>>>(Wq, Wk, Wv, Wsk, Wt);
  hipMemsetAsync(tmp, 0, 4 * L_CNT * 4, stream);
  k_hist<<<dim3(1172, 4), 256, 0, stream>>>(eidx, tmp);
  k_scan1<<<dim3(74, 4), 256, 0, stream>>>(tmp, rowptr, bsum);
  k_scan2<<<4, 128, 0, stream>>>(bsum);
  k_scan3<<<dim3(592, 4), 256, 0, stream>>>(rowptr, tmp, bsum);
  k_scatter<<<dim3(1172, 4), 256, 0, stream>>>(eidx, tmp, sorted);

  for (int l = 0; l < 4; ++l) {
    const int* srcA = eidx + (size_t)l * 600000;
    const int* dstA = srcA + 300000;
    const int* sortedE = sorted + (size_t)l * E_EDGES;
    const int* rpl = rowptr + (size_t)l * L_CNT;
    const u16* WtQl = Wt + (size_t)l * 16384;
    const u16* WtKl = Wt + (size_t)(4 + l) * 16384;
    const u16* WtVl = Wt + (size_t)(8 + l) * 16384;
    const u16* WtSl = Wt + (size_t)(12 + l) * 16384;
    const float* Wal = Wa + (size_t)l * 1024;
    const float* attrl = attr + (size_t)l * 2400000;
    const float* dtl = dt + (size_t)l * 300000;
    const float* dsl = dsv + (size_t)l * 300000;
    const int* etl = etyp + (size_t)l * 300000;

    hipMemsetAsync(colsum, 0, 1024, stream);

    if (l == 0) {
      gemm_qs<1><<<1172, 256, 0, stream>>>((const void*)x0, WtQl, WtSl, Q, S);
      edge_pass<1><<<2344, 256, 0, stream>>>(
          (const void*)x0, WtKl, WtVl, Wal, tw, tb, dw, db, ttab, attrl,
          dtl, dsl, srcA, dstA, etl, sortedE, Q, logits, Vs);
    } else {
      gemm_qs<0><<<1172, 256, 0, stream>>>((const void*)xbf, WtQl, WtSl, Q, S);
      edge_pass<0><<<2344, 256, 0, stream>>>(
          (const void*)xbf, WtKl, WtVl, Wal, tw, tb, dw, db, ttab, attrl,
          dtl, dsl, srcA, dstA, etl, sortedE, Q, logits, Vs);
    }

    node_agg<<<1172, 256, 0, stream>>>(Vs, logits, rpl, S, betaP + l,
                                       pre, colsum, colsumsq);

    if (l < 3)
      bn_apply<0><<<18750, 256, 0, stream>>>(pre, colsum, colsumsq,
                                             gam + (size_t)l * 128,
                                             bet + (size_t)l * 128, xbf, nullptr);
    else
      bn_apply<1><<<18750, 256, 0, stream>>>(pre, colsum, colsumsq,
                                             gam + (size_t)l * 128,
                                             bet + (size_t)l * 128,
                                             nullptr, (float*)d_out);
  }
}

// Round 6
// 1733.427 us; speedup vs baseline: 3.6628x; 1.2444x over previous
//
#include <hip/hip_runtime.h>

typedef unsigned int u32;
typedef unsigned short u16;
typedef short bf16x8 __attribute__((ext_vector_type(8)));
typedef float f32x4 __attribute__((ext_vector_type(4)));

#define N_NODES 150000
#define E_EDGES 300000
#define L_CNT   151552   // 74*2048 padded per-layer node stride

__device__ __forceinline__ float b2f(u16 h){ return __uint_as_float(((u32)h) << 16); }
__device__ __forceinline__ u16 f2bf(float f){
  u32 u = __float_as_uint(f);
  return (u16)((u + 0x7fffu + ((u >> 16) & 1u)) >> 16);   // RNE
}

__device__ __forceinline__ f32x4 mfma16(bf16x8 a, bf16x8 b, f32x4 c){
  return __builtin_amdgcn_mfma_f32_16x16x32_bf16(a, b, c, 0, 0, 0);
}

// operand tile [r][128k] u16, XOR-swizzled: conflict-free writes, ~2-way reads
__device__ __forceinline__ int opsw(int r, int k){ return (r * 128 + k) ^ ((r & 7) << 3); }
// C tile [r][128n] u16 swizzle (spreads the 4 row-groups of the MFMA C layout)
__device__ __forceinline__ int csw(int r, int n){ return (r * 128 + n) ^ (((r >> 2) & 3) << 3); }

// ---------------- weight pre-transpose: Wt[n][k] bf16 <- W[k][n] f32 ----------------
__global__ __launch_bounds__(256)
void k_wt(const float* __restrict__ Wq, const float* __restrict__ Wk,
          const float* __restrict__ Wv, const float* __restrict__ Ws,
          u16* __restrict__ Wt)
{
  const int m = blockIdx.x;   // 0..15: [Wq0-3, Wk0-3, Wv0-3, Wsk0-3]
  const float* src = (m < 4 ? Wq : m < 8 ? Wk : m < 12 ? Wv : Ws)
                     + (size_t)(m & 3) * 16384;
  u16* dst = Wt + (size_t)m * 16384;
  const int t = threadIdx.x;
  for (int i = 0; i < 16; ++i) {
    int idx = i * 256 + t;            // 4096 quads
    int n = idx >> 5;
    int k4 = (idx & 31) << 2;
    ushort4 o;
    o.x = f2bf(src[(k4 + 0) * 128 + n]);
    o.y = f2bf(src[(k4 + 1) * 128 + n]);
    o.z = f2bf(src[(k4 + 2) * 128 + n]);
    o.w = f2bf(src[(k4 + 3) * 128 + n]);
    *(ushort4*)(dst + n * 128 + k4) = o;
  }
}

// ---------------- shared device helpers ----------------

__device__ __forceinline__ void acc_zero(f32x4 (&acc)[2][8])
{
  #pragma unroll
  for (int a = 0; a < 2; ++a)
    #pragma unroll
    for (int b = 0; b < 8; ++b) {
      acc[a][b][0] = 0.f; acc[a][b][1] = 0.f;
      acc[a][b][2] = 0.f; acc[a][b][3] = 0.f;
    }
}

// vacc[eb][nb] reg j -> C[row = w*32 + eb*16 + (lane>>4)*4 + j][col = nb*16 + (lane&15)]
__device__ __forceinline__ void acc_to_lds(u16* Cs, f32x4 (&acc)[2][8], int w, int lane)
{
  const int lr = lane & 15;
  const int g4 = (lane >> 4) << 2;
  #pragma unroll
  for (int mt = 0; mt < 2; ++mt)
    #pragma unroll
    for (int nt = 0; nt < 8; ++nt)
      #pragma unroll
      for (int j = 0; j < 4; ++j)
        Cs[csw(w * 32 + mt * 16 + g4 + j, nt * 16 + lr)] = f2bf(acc[mt][nt][j]);
}

__device__ __forceinline__ void lds_to_global(const u16* Cs, u16* __restrict__ G,
                                              int base, int nr, int t)
{
  #pragma unroll
  for (int i = 0; i < 8; ++i) {
    int cid = i * 256 + t;
    int r = cid >> 4, n8 = (cid & 15) << 3;
    if (r < nr) {
      uint4 v = *(const uint4*)(Cs + csw(r, n8));
      *(uint4*)(G + (size_t)(base + r) * 128 + n8) = v;
    }
  }
}

// ---------------- CSR build (counting sort of edges by dst) ----------------

__global__ __launch_bounds__(256)
void k_hist(const int* __restrict__ eidx, int* __restrict__ counts)
{
  const int l = blockIdx.y;
  const int e = blockIdx.x * 256 + threadIdx.x;
  if (e < E_EDGES) {
    int dst = eidx[(size_t)l * 2 * E_EDGES + E_EDGES + e];
    atomicAdd(&counts[(size_t)l * L_CNT + dst], 1);
  }
}

__global__ __launch_bounds__(256)
void k_scan1(const int* __restrict__ counts, int* __restrict__ rowptr,
             int* __restrict__ bsum)
{
  __shared__ int sh[256];
  const int b = blockIdx.x, l = blockIdx.y;
  const int t = threadIdx.x;
  const int* c = counts + (size_t)l * L_CNT + b * 2048;
  int* rp = rowptr + (size_t)l * L_CNT + b * 2048;
  int v[8]; int s = 0;
  #pragma unroll
  for (int j = 0; j < 8; ++j) { v[j] = c[t * 8 + j]; s += v[j]; }
  sh[t] = s; __syncthreads();
  for (int off = 1; off < 256; off <<= 1) {
    int x = (t >= off) ? sh[t - off] : 0;
    __syncthreads();
    sh[t] += x;
    __syncthreads();
  }
  int excl = (t == 0) ? 0 : sh[t - 1];
  if (t == 255) bsum[l * 128 + b] = sh[255];
  int run = excl;
  #pragma unroll
  for (int j = 0; j < 8; ++j) { rp[t * 8 + j] = run; run += v[j]; }
}

__global__ __launch_bounds__(128)
void k_scan2(int* __restrict__ bsum)
{
  __shared__ int sh[128];
  const int l = blockIdx.x, t = threadIdx.x;
  int v = (t < 74) ? bsum[l * 128 + t] : 0;
  sh[t] = v; __syncthreads();
  for (int off = 1; off < 128; off <<= 1) {
    int x = (t >= off) ? sh[t - off] : 0;
    __syncthreads();
    sh[t] += x;
    __syncthreads();
  }
  int excl = (t == 0) ? 0 : sh[t - 1];
  if (t < 74) bsum[l * 128 + t] = excl;
}

__global__ __launch_bounds__(256)
void k_scan3(int* __restrict__ rowptr, int* __restrict__ tmp,
             const int* __restrict__ bsum)
{
  const int l = blockIdx.y;
  const int q = blockIdx.x * 256 + threadIdx.x;
  int v = rowptr[(size_t)l * L_CNT + q] + bsum[l * 128 + (q >> 11)];
  rowptr[(size_t)l * L_CNT + q] = v;
  tmp[(size_t)l * L_CNT + q] = v;
}

__global__ __launch_bounds__(256)
void k_scatter(const int* __restrict__ eidx, int* __restrict__ tmp,
               int* __restrict__ sorted)
{
  const int l = blockIdx.y;
  const int e = blockIdx.x * 256 + threadIdx.x;
  if (e < E_EDGES) {
    int dst = eidx[(size_t)l * 2 * E_EDGES + E_EDGES + e];
    int pos = atomicAdd(&tmp[(size_t)l * L_CNT + dst], 1);
    sorted[(size_t)l * E_EDGES + pos] = e;
  }
}

// ---------------- node GEMM: Q = x@Wq, S = x@Wskip (MFMA, B from global) ----------------

template<int XF32>
__global__ __launch_bounds__(256)
void gemm_qs(const void* __restrict__ xg, const u16* __restrict__ WtQ,
             const u16* __restrict__ WtS, u16* __restrict__ Qo,
             u16* __restrict__ So)
{
  __shared__ __align__(16) u16 As[16384];
  const int t = threadIdx.x;
  const int w = t >> 6, lane = t & 63;
  const int lr = lane & 15, hi = lane >> 4;
  const int row0 = blockIdx.x * 128;
  const int g = t >> 5, c4 = (t & 31) << 2;
  int nr = N_NODES - row0; if (nr > 128) nr = 128;

  // stage x tile -> As [r][k]
  #pragma unroll
  for (int i = 0; i < 16; ++i) {
    int r = i * 8 + g;
    ushort4 o = make_ushort4(0, 0, 0, 0);
    if (r < nr) {
      if (XF32) {
        float4 v = *(const float4*)((const float*)xg + (size_t)(row0 + r) * 128 + c4);
        o.x = f2bf(v.x); o.y = f2bf(v.y); o.z = f2bf(v.z); o.w = f2bf(v.w);
      } else {
        o = *(const ushort4*)((const u16*)xg + (size_t)(row0 + r) * 128 + c4);
      }
    }
    *(ushort4*)(As + opsw(r, c4)) = o;
  }
  __syncthreads();

  f32x4 qacc[2][8], sacc[2][8];
  acc_zero(qacc); acc_zero(sacc);
  #pragma unroll
  for (int ks = 0; ks < 4; ++ks) {
    const int kb = ks * 32 + hi * 8;
    bf16x8 a0 = *(const bf16x8*)(As + opsw(w * 32 + lr, kb));
    bf16x8 a1 = *(const bf16x8*)(As + opsw(w * 32 + 16 + lr, kb));
    #pragma unroll
    for (int nb = 0; nb < 8; ++nb) {
      bf16x8 bq = *(const bf16x8*)(WtQ + (nb * 16 + lr) * 128 + kb);
      bf16x8 bs = *(const bf16x8*)(WtS + (nb * 16 + lr) * 128 + kb);
      qacc[0][nb] = mfma16(a0, bq, qacc[0][nb]);
      qacc[1][nb] = mfma16(a1, bq, qacc[1][nb]);
      sacc[0][nb] = mfma16(a0, bs, sacc[0][nb]);
      sacc[1][nb] = mfma16(a1, bs, sacc[1][nb]);
    }
  }
  __syncthreads();
  acc_to_lds(As, qacc, w, lane);
  __syncthreads();
  lds_to_global(As, Qo, row0, nr, t);
  __syncthreads();
  acc_to_lds(As, sacc, w, lane);
  __syncthreads();
  lds_to_global(As, So, row0, nr, t);
}

// ---------------- fused edge kernel ----------------
// stage features -> As; K GEMM swapped (D[n][e], col=edge per lane) -> logits
// straight from accs (per-lane Q[dst] dot + 2 shfl); V GEMM; As reused as C tile.

template<int XF32>
__global__ __launch_bounds__(256)
void edge_pass(const void* __restrict__ xg, const u16* __restrict__ WtK,
               const u16* __restrict__ WtV, const float* __restrict__ Wa,
               const float* __restrict__ tw, const float* __restrict__ tb,
               const float* __restrict__ dw, const float* __restrict__ db,
               const float* __restrict__ ttab, const float* __restrict__ attr,
               const float* __restrict__ dt, const float* __restrict__ dsv,
               const int* __restrict__ srcA, const int* __restrict__ dstA,
               const int* __restrict__ etA, const int* __restrict__ sortedE,
               const u16* __restrict__ Qb, float* __restrict__ logits,
               u16* __restrict__ Vs)
{
  __shared__ __align__(16) u16 As[16384];
  __shared__ int dstSh[128];
  const int t = threadIdx.x;
  const int w = t >> 6, lane = t & 63;
  const int lr = lane & 15, hi = lane >> 4;
  const int e0 = blockIdx.x * 128;
  const int ne = min(128, E_EDGES - e0);
  const int g = t >> 5, c4 = (t & 31) << 2;

  float4 tw4 = *(const float4*)(tw + c4);
  float4 tb4 = *(const float4*)(tb + c4);
  float4 dw4 = *(const float4*)(dw + c4);
  float4 db4 = *(const float4*)(db + c4);
  float4 wa4[8];
  #pragma unroll
  for (int a = 0; a < 8; ++a) wa4[a] = *(const float4*)(Wa + a * 128 + c4);

  // stage kv_in = x[src] + attr@Wa + cos(dt*tw+tb) + cos(ds*dw+db) + tt[et]
  #pragma unroll
  for (int i = 0; i < 16; ++i) {
    int r = i * 8 + g;
    ushort4 o = make_ushort4(0, 0, 0, 0);
    if (r < ne) {
      int eid = sortedE[e0 + r];
      if ((t & 31) == 0) dstSh[r] = dstA[eid];
      int et = etA[eid];
      float dtn = dt[eid] * (1.0f / 24.0f);
      float dss = dsv[eid];
      float4 tt4 = *(const float4*)(ttab + et * 128 + c4);
      float f0 = __cosf(fmaf(dtn, tw4.x, tb4.x)) + __cosf(fmaf(dss, dw4.x, db4.x)) + tt4.x;
      float f1 = __cosf(fmaf(dtn, tw4.y, tb4.y)) + __cosf(fmaf(dss, dw4.y, db4.y)) + tt4.y;
      float f2 = __cosf(fmaf(dtn, tw4.z, tb4.z)) + __cosf(fmaf(dss, dw4.z, db4.z)) + tt4.z;
      float f3 = __cosf(fmaf(dtn, tw4.w, tb4.w)) + __cosf(fmaf(dss, dw4.w, db4.w)) + tt4.w;
      const float* ap = attr + (size_t)eid * 8;
      #pragma unroll
      for (int a = 0; a < 8; ++a) {
        float aa = ap[a];
        f0 = fmaf(aa, wa4[a].x, f0);
        f1 = fmaf(aa, wa4[a].y, f1);
        f2 = fmaf(aa, wa4[a].z, f2);
        f3 = fmaf(aa, wa4[a].w, f3);
      }
      int src = srcA[eid];
      float x0, x1, x2, x3;
      if (XF32) {
        float4 xr = *(const float4*)((const float*)xg + (size_t)src * 128 + c4);
        x0 = xr.x; x1 = xr.y; x2 = xr.z; x3 = xr.w;
      } else {
        ushort4 xr = *(const ushort4*)((const u16*)xg + (size_t)src * 128 + c4);
        x0 = b2f(xr.x); x1 = b2f(xr.y); x2 = b2f(xr.z); x3 = b2f(xr.w);
      }
      o.x = f2bf(x0 + f0);
      o.y = f2bf(x1 + f1);
      o.z = f2bf(x2 + f2);
      o.w = f2bf(x3 + f3);
    } else {
      if ((t & 31) == 0) dstSh[r] = 0;   // safe Q gather for pad rows
    }
    *(ushort4*)(As + opsw(r, c4)) = o;
  }
  __syncthreads();

  // ---- K GEMM, swapped operands: D[i=n][j=edge]; kacc[eb][nb] ----
  f32x4 kacc[2][8];
  acc_zero(kacc);
  #pragma unroll
  for (int ks = 0; ks < 4; ++ks) {
    const int kb = ks * 32 + hi * 8;
    bf16x8 ef0 = *(const bf16x8*)(As + opsw(w * 32 + lr, kb));        // edge cols
    bf16x8 ef1 = *(const bf16x8*)(As + opsw(w * 32 + 16 + lr, kb));
    #pragma unroll
    for (int nb = 0; nb < 8; ++nb) {
      bf16x8 af = *(const bf16x8*)(WtK + (nb * 16 + lr) * 128 + kb);  // A rows = n
      kacc[0][nb] = mfma16(af, ef0, kacc[0][nb]);
      kacc[1][nb] = mfma16(af, ef1, kacc[1][nb]);
    }
  }

  // logits from kacc: lane owns edge el = w*32+eb*16+lr; K[el][n=nb*16+hi*4+j]
  #pragma unroll
  for (int eb = 0; eb < 2; ++eb) {
    int el = w * 32 + eb * 16 + lr;
    int dstn = dstSh[el];
    float hs[4] = {0.f, 0.f, 0.f, 0.f};
    #pragma unroll
    for (int nb = 0; nb < 8; ++nb) {
      ushort4 q = *(const ushort4*)(Qb + (size_t)dstn * 128 + nb * 16 + hi * 4);
      hs[nb >> 1] += b2f(q.x) * kacc[eb][nb][0] + b2f(q.y) * kacc[eb][nb][1]
                   + b2f(q.z) * kacc[eb][nb][2] + b2f(q.w) * kacc[eb][nb][3];
    }
    #pragma unroll
    for (int h = 0; h < 4; ++h) {
      hs[h] += __shfl_xor(hs[h], 16, 64);
      hs[h] += __shfl_xor(hs[h], 32, 64);
      hs[h] *= 0.17677669529663687f;                 // 32^-0.5
      hs[h] = (hs[h] >= 0.f) ? hs[h] : 0.2f * hs[h]; // leaky relu
    }
    if (lane < 16 && el < ne)
      *(float4*)(logits + (size_t)(e0 + el) * 4) = make_float4(hs[0], hs[1], hs[2], hs[3]);
  }

  // ---- V GEMM, normal orientation: D[i=edge][j=n] ----
  f32x4 vacc[2][8];
  acc_zero(vacc);
  #pragma unroll
  for (int ks = 0; ks < 4; ++ks) {
    const int kb = ks * 32 + hi * 8;
    bf16x8 af0 = *(const bf16x8*)(As + opsw(w * 32 + lr, kb));
    bf16x8 af1 = *(const bf16x8*)(As + opsw(w * 32 + 16 + lr, kb));
    #pragma unroll
    for (int nb = 0; nb < 8; ++nb) {
      bf16x8 bf = *(const bf16x8*)(WtV + (nb * 16 + lr) * 128 + kb);
      vacc[0][nb] = mfma16(af0, bf, vacc[0][nb]);
      vacc[1][nb] = mfma16(af1, bf, vacc[1][nb]);
    }
  }
  __syncthreads();                 // all As reads complete
  acc_to_lds(As, vacc, w, lane);   // reuse As as C tile
  __syncthreads();
  lds_to_global(As, Vs, e0, ne, t);
}

// ---------------- per-node softmax + aggregate + combine + stats ----------------
__global__ __launch_bounds__(256)
void node_agg(const u16* __restrict__ Vs, const float* __restrict__ logits,
              const int* __restrict__ rowptr, const u16* __restrict__ S,
              const float* __restrict__ betaP, float* __restrict__ pre,
              float* __restrict__ colsum, float* __restrict__ colsumsq)
{
  __shared__ float red[1024];
  const int t = threadIdx.x;
  const int g = t >> 5;
  const int lane = t & 31;
  const int d0 = lane * 4;
  const int h = lane >> 3;
  const float beta = *betaP;
  const float omb = 1.f - beta;
  float s4[4] = {0.f, 0.f, 0.f, 0.f};
  float q4[4] = {0.f, 0.f, 0.f, 0.f};
  for (int rep = 0; rep < 16; ++rep) {
    int n = blockIdx.x * 128 + rep * 8 + g;
    if (n < N_NODES) {
      int rs = rowptr[n], re = rowptr[n + 1];
      float m = -1e30f;
      for (int i = rs; i < re; ++i)
        m = fmaxf(m, logits[(size_t)i * 4 + h]);
      float den = 0.f;
      float a0 = 0.f, a1 = 0.f, a2 = 0.f, a3 = 0.f;
      for (int i = rs; i < re; ++i) {
        float wgt = __expf(logits[(size_t)i * 4 + h] - m);
        den += wgt;
        ushort4 v = *(const ushort4*)(Vs + (size_t)i * 128 + d0);
        a0 = fmaf(wgt, b2f(v.x), a0);
        a1 = fmaf(wgt, b2f(v.y), a1);
        a2 = fmaf(wgt, b2f(v.z), a2);
        a3 = fmaf(wgt, b2f(v.w), a3);
      }
      float inv = (den > 0.f) ? (omb / den) : 0.f;
      ushort4 sv = *(const ushort4*)(S + (size_t)n * 128 + d0);
      float p0 = fmaf(beta, b2f(sv.x), a0 * inv);
      float p1 = fmaf(beta, b2f(sv.y), a1 * inv);
      float p2 = fmaf(beta, b2f(sv.z), a2 * inv);
      float p3 = fmaf(beta, b2f(sv.w), a3 * inv);
      *(float4*)(pre + (size_t)n * 128 + d0) = make_float4(p0, p1, p2, p3);
      s4[0] += p0; s4[1] += p1; s4[2] += p2; s4[3] += p3;
      q4[0] += p0 * p0; q4[1] += p1 * p1; q4[2] += p2 * p2; q4[3] += p3 * p3;
    }
  }
  *(float4*)(&red[g * 128 + d0]) = make_float4(s4[0], s4[1], s4[2], s4[3]);
  __syncthreads();
  if (t < 128) {
    float tot = 0.f;
    #pragma unroll
    for (int gg = 0; gg < 8; ++gg) tot += red[gg * 128 + t];
    atomicAdd(&colsum[t], tot);
  }
  __syncthreads();
  *(float4*)(&red[g * 128 + d0]) = make_float4(q4[0], q4[1], q4[2], q4[3]);
  __syncthreads();
  if (t < 128) {
    float tot = 0.f;
    #pragma unroll
    for (int gg = 0; gg < 8; ++gg) tot += red[gg * 128 + t];
    atomicAdd(&colsumsq[t], tot);
  }
}

// ---------------- BatchNorm(train stats) + ReLU ----------------
template<int LAST>
__global__ __launch_bounds__(256)
void bn_apply(const float* __restrict__ pre, const float* __restrict__ colsum,
              const float* __restrict__ colsumsq, const float* __restrict__ gamma,
              const float* __restrict__ bvec, u16* __restrict__ outbf,
              float* __restrict__ outf)
{
  const int idx = blockIdx.x * 256 + threadIdx.x;
  const int n = idx >> 5;
  const int d0 = (idx & 31) * 4;
  const float invN = 1.f / 150000.f;
  float4 p = *(const float4*)(pre + (size_t)n * 128 + d0);
  float4 cs = *(const float4*)(colsum + d0);
  float4 cq = *(const float4*)(colsumsq + d0);
  float4 gm = *(const float4*)(gamma + d0);
  float4 bv = *(const float4*)(bvec + d0);
  float mu, var, y;
  mu = cs.x * invN; var = cq.x * invN - mu * mu;
  y = (p.x - mu) * rsqrtf(var + 1e-5f) * gm.x + bv.x; p.x = fmaxf(y, 0.f);
  mu = cs.y * invN; var = cq.y * invN - mu * mu;
  y = (p.y - mu) * rsqrtf(var + 1e-5f) * gm.y + bv.y; p.y = fmaxf(y, 0.f);
  mu = cs.z * invN; var = cq.z * invN - mu * mu;
  y = (p.z - mu) * rsqrtf(var + 1e-5f) * gm.z + bv.z; p.z = fmaxf(y, 0.f);
  mu = cs.w * invN; var = cq.w * invN - mu * mu;
  y = (p.w - mu) * rsqrtf(var + 1e-5f) * gm.w + bv.w; p.w = fmaxf(y, 0.f);
  if (LAST) {
    *(float4*)(outf + (size_t)n * 128 + d0) = p;
  } else {
    ushort4 o;
    o.x = f2bf(p.x); o.y = f2bf(p.y); o.z = f2bf(p.z); o.w = f2bf(p.w);
    *(ushort4*)(outbf + (size_t)n * 128 + d0) = o;
  }
}

extern "C" void kernel_launch(void* const* d_in, const int* in_sizes, int n_in,
                              void* d_out, int out_size, void* d_ws, size_t ws_size,
                              hipStream_t stream)
{
  const float* x0    = (const float*)d_in[0];
  const float* Wq    = (const float*)d_in[1];
  const float* Wk    = (const float*)d_in[2];
  const float* Wv    = (const float*)d_in[3];
  const float* Wsk   = (const float*)d_in[4];
  const float* Wa    = (const float*)d_in[5];
  const float* tw    = (const float*)d_in[6];
  const float* tb    = (const float*)d_in[7];
  const float* dw    = (const float*)d_in[8];
  const float* db    = (const float*)d_in[9];
  const float* ttab  = (const float*)d_in[10];
  const float* gam   = (const float*)d_in[11];
  const float* bet   = (const float*)d_in[12];
  const float* betaP = (const float*)d_in[13];
  const float* attr  = (const float*)d_in[14];
  const float* dt    = (const float*)d_in[15];
  const float* dsv   = (const float*)d_in[16];
  const int*   eidx  = (const int*)d_in[17];
  const int*   etyp  = (const int*)d_in[18];

  // workspace ~207 MB
  char* p = (char*)d_ws;
  u16* xbf  = (u16*)p;       p += 38400000;          // [N,128] bf16
  u16* Q    = (u16*)p;       p += 38400000;          // [N,128] bf16
  u16* S    = (u16*)p;       p += 38400000;          // [N,128] bf16
  u16* Vs   = (u16*)p;       p += 76800000;          // [E,128] bf16 dst-sorted
  float* logits = (float*)p; p += 4800000;           // [E,4] f32 dst-sorted
  int* rowptr = (int*)p;     p += 4 * L_CNT * 4;
  int* tmp    = (int*)p;     p += 4 * L_CNT * 4;
  int* sorted = (int*)p;     p += 4 * E_EDGES * 4;
  int* bsum   = (int*)p;     p += 4 * 128 * 4;
  float* colsum   = (float*)p; p += 512;
  float* colsumsq = (float*)p; p += 512;
  u16* Wt = (u16*)p;         p += 16 * 16384 * 2;    // 16 transposed bf16 weights

  float* pre = (float*)d_out;   // [N,128] f32 scratch (final bn overwrites)

  // weight transpose + CSR build
  k_wt<<<16, 256, 0, stream>>>(Wq, Wk, Wv, Wsk, Wt);
  hipMemsetAsync(tmp, 0, 4 * L_CNT * 4, stream);
  k_hist<<<dim3(1172, 4), 256, 0, stream>>>(eidx, tmp);
  k_scan1<<<dim3(74, 4), 256, 0, stream>>>(tmp, rowptr, bsum);
  k_scan2<<<4, 128, 0, stream>>>(bsum);
  k_scan3<<<dim3(592, 4), 256, 0, stream>>>(rowptr, tmp, bsum);
  k_scatter<<<dim3(1172, 4), 256, 0, stream>>>(eidx, tmp, sorted);

  for (int l = 0; l < 4; ++l) {
    const int* srcA = eidx + (size_t)l * 600000;
    const int* dstA = srcA + 300000;
    const int* sortedE = sorted + (size_t)l * E_EDGES;
    const int* rpl = rowptr + (size_t)l * L_CNT;
    const u16* WtQl = Wt + (size_t)l * 16384;
    const u16* WtKl = Wt + (size_t)(4 + l) * 16384;
    const u16* WtVl = Wt + (size_t)(8 + l) * 16384;
    const u16* WtSl = Wt + (size_t)(12 + l) * 16384;
    const float* Wal = Wa + (size_t)l * 1024;
    const float* attrl = attr + (size_t)l * 2400000;
    const float* dtl = dt + (size_t)l * 300000;
    const float* dsl = dsv + (size_t)l * 300000;
    const int* etl = etyp + (size_t)l * 300000;

    hipMemsetAsync(colsum, 0, 1024, stream);

    if (l == 0) {
      gemm_qs<1><<<1172, 256, 0, stream>>>((const void*)x0, WtQl, WtSl, Q, S);
      edge_pass<1><<<2344, 256, 0, stream>>>(
          (const void*)x0, WtKl, WtVl, Wal, tw, tb, dw, db, ttab, attrl,
          dtl, dsl, srcA, dstA, etl, sortedE, Q, logits, Vs);
    } else {
      gemm_qs<0><<<1172, 256, 0, stream>>>((const void*)xbf, WtQl, WtSl, Q, S);
      edge_pass<0><<<2344, 256, 0, stream>>>(
          (const void*)xbf, WtKl, WtVl, Wal, tw, tb, dw, db, ttab, attrl,
          dtl, dsl, srcA, dstA, etl, sortedE, Q, logits, Vs);
    }

    node_agg<<<1172, 256, 0, stream>>>(Vs, logits, rpl, S, betaP + l,
                                       pre, colsum, colsumsq);

    if (l < 3)
      bn_apply<0><<<18750, 256, 0, stream>>>(pre, colsum, colsumsq,
                                             gam + (size_t)l * 128,
                                             bet + (size_t)l * 128, xbf, nullptr);
    else
      bn_apply<1><<<18750, 256, 0, stream>>>(pre, colsum, colsumsq,
                                             gam + (size_t)l * 128,
                                             bet + (size_t)l * 128,
                                             nullptr, (float*)d_out);
  }
}

// Round 7
// 1707.482 us; speedup vs baseline: 3.7185x; 1.0152x over previous
//
#include <hip/hip_runtime.h>

typedef unsigned int u32;
typedef unsigned short u16;
typedef short bf16x8 __attribute__((ext_vector_type(8)));
typedef float f32x4 __attribute__((ext_vector_type(4)));

#define N_NODES 150000
#define E_EDGES 300000
#define L_CNT   151552   // 74*2048 padded per-layer node stride

__device__ __forceinline__ float b2f(u16 h){ return __uint_as_float(((u32)h) << 16); }
__device__ __forceinline__ u16 f2bf(float f){
  u32 u = __float_as_uint(f);
  return (u16)((u + 0x7fffu + ((u >> 16) & 1u)) >> 16);   // RNE
}

__device__ __forceinline__ f32x4 mfma16(bf16x8 a, bf16x8 b, f32x4 c){
  return __builtin_amdgcn_mfma_f32_16x16x32_bf16(a, b, c, 0, 0, 0);
}

// wave-private operand tile [r=0..31][k=0..127] u16, XOR-swizzled
__device__ __forceinline__ int opsw(int r, int k){ return (r * 128 + k) ^ ((r & 7) << 3); }
// wave-private C tile [r][n] swizzle
__device__ __forceinline__ int csw(int r, int n){ return (r * 128 + n) ^ (((r >> 2) & 3) << 3); }

// ---------------- weight pre-transpose: Wt[n][k] bf16 <- W[k][n] f32 ----------------
__global__ __launch_bounds__(256)
void k_wt(const float* __restrict__ Wq, const float* __restrict__ Wk,
          const float* __restrict__ Wv, const float* __restrict__ Ws,
          u16* __restrict__ Wt)
{
  const int m = blockIdx.x;   // 0..15: [Wq0-3, Wk0-3, Wv0-3, Wsk0-3]
  const float* src = (m < 4 ? Wq : m < 8 ? Wk : m < 12 ? Wv : Ws)
                     + (size_t)(m & 3) * 16384;
  u16* dst = Wt + (size_t)m * 16384;
  const int t = threadIdx.x;
  for (int i = 0; i < 16; ++i) {
    int idx = i * 256 + t;
    int n = idx >> 5;
    int k4 = (idx & 31) << 2;
    ushort4 o;
    o.x = f2bf(src[(k4 + 0) * 128 + n]);
    o.y = f2bf(src[(k4 + 1) * 128 + n]);
    o.z = f2bf(src[(k4 + 2) * 128 + n]);
    o.w = f2bf(src[(k4 + 3) * 128 + n]);
    *(ushort4*)(dst + n * 128 + k4) = o;
  }
}

// ---------------- shared device helpers (wave-local, barrier-free) ----------------

__device__ __forceinline__ void acc_zero(f32x4 (&acc)[2][8])
{
  #pragma unroll
  for (int a = 0; a < 2; ++a)
    #pragma unroll
    for (int b = 0; b < 8; ++b) {
      acc[a][b][0] = 0.f; acc[a][b][1] = 0.f;
      acc[a][b][2] = 0.f; acc[a][b][3] = 0.f;
    }
}

// acc[eb][nb] reg j -> C[row = eb*16 + (lane>>4)*4 + j][col = nb*16 + (lane&15)]
__device__ __forceinline__ void acc_to_lds(u16* Cs, f32x4 (&acc)[2][8], int lane)
{
  const int lr = lane & 15;
  const int g4 = (lane >> 4) << 2;
  #pragma unroll
  for (int mt = 0; mt < 2; ++mt)
    #pragma unroll
    for (int nt = 0; nt < 8; ++nt)
      #pragma unroll
      for (int j = 0; j < 4; ++j)
        Cs[csw(mt * 16 + g4 + j, nt * 16 + lr)] = f2bf(acc[mt][nt][j]);
}

// 32 rows x 128 u16 -> global, coalesced (8 iters x 64 lanes x 16B)
__device__ __forceinline__ void lds_to_global(const u16* Cs, u16* __restrict__ G,
                                              int base, int nr, int lane)
{
  #pragma unroll
  for (int i = 0; i < 8; ++i) {
    int idx = i * 64 + lane;
    int r = idx >> 4, n8 = (idx & 15) << 3;
    if (r < nr) {
      uint4 v = *(const uint4*)(Cs + csw(r, n8));
      *(uint4*)(G + (size_t)(base + r) * 128 + n8) = v;
    }
  }
}

// ---------------- CSR build (counting sort of edges by dst) ----------------

__global__ __launch_bounds__(256)
void k_hist(const int* __restrict__ eidx, int* __restrict__ counts)
{
  const int l = blockIdx.y;
  const int e = blockIdx.x * 256 + threadIdx.x;
  if (e < E_EDGES) {
    int dst = eidx[(size_t)l * 2 * E_EDGES + E_EDGES + e];
    atomicAdd(&counts[(size_t)l * L_CNT + dst], 1);
  }
}

__global__ __launch_bounds__(256)
void k_scan1(const int* __restrict__ counts, int* __restrict__ rowptr,
             int* __restrict__ bsum)
{
  __shared__ int sh[256];
  const int b = blockIdx.x, l = blockIdx.y;
  const int t = threadIdx.x;
  const int* c = counts + (size_t)l * L_CNT + b * 2048;
  int* rp = rowptr + (size_t)l * L_CNT + b * 2048;
  int v[8]; int s = 0;
  #pragma unroll
  for (int j = 0; j < 8; ++j) { v[j] = c[t * 8 + j]; s += v[j]; }
  sh[t] = s; __syncthreads();
  for (int off = 1; off < 256; off <<= 1) {
    int x = (t >= off) ? sh[t - off] : 0;
    __syncthreads();
    sh[t] += x;
    __syncthreads();
  }
  int excl = (t == 0) ? 0 : sh[t - 1];
  if (t == 255) bsum[l * 128 + b] = sh[255];
  int run = excl;
  #pragma unroll
  for (int j = 0; j < 8; ++j) { rp[t * 8 + j] = run; run += v[j]; }
}

__global__ __launch_bounds__(128)
void k_scan2(int* __restrict__ bsum)
{
  __shared__ int sh[128];
  const int l = blockIdx.x, t = threadIdx.x;
  int v = (t < 74) ? bsum[l * 128 + t] : 0;
  sh[t] = v; __syncthreads();
  for (int off = 1; off < 128; off <<= 1) {
    int x = (t >= off) ? sh[t - off] : 0;
    __syncthreads();
    sh[t] += x;
    __syncthreads();
  }
  int excl = (t == 0) ? 0 : sh[t - 1];
  if (t < 74) bsum[l * 128 + t] = excl;
}

__global__ __launch_bounds__(256)
void k_scan3(int* __restrict__ rowptr, int* __restrict__ tmp,
             const int* __restrict__ bsum)
{
  const int l = blockIdx.y;
  const int q = blockIdx.x * 256 + threadIdx.x;
  int v = rowptr[(size_t)l * L_CNT + q] + bsum[l * 128 + (q >> 11)];
  rowptr[(size_t)l * L_CNT + q] = v;
  tmp[(size_t)l * L_CNT + q] = v;
}

__global__ __launch_bounds__(256)
void k_scatter(const int* __restrict__ eidx, int* __restrict__ tmp,
               int* __restrict__ sorted)
{
  const int l = blockIdx.y;
  const int e = blockIdx.x * 256 + threadIdx.x;
  if (e < E_EDGES) {
    int dst = eidx[(size_t)l * 2 * E_EDGES + E_EDGES + e];
    int pos = atomicAdd(&tmp[(size_t)l * L_CNT + dst], 1);
    sorted[(size_t)l * E_EDGES + pos] = e;
  }
}

// ---------------- node GEMM: Q,S = x @ {Wq,Wskip}; per-wave 32-node tile, no barriers ----------------

template<int XF32>
__global__ __launch_bounds__(256)
void gemm_qs(const void* __restrict__ xg, const u16* __restrict__ WtQ,
             const u16* __restrict__ WtS, u16* __restrict__ Qo,
             u16* __restrict__ So)
{
  __shared__ __align__(16) u16 AsAll[4][4160];
  const int t = threadIdx.x;
  const int w = t >> 6, lane = t & 63;
  u16* As = AsAll[w];
  const int lr = lane & 15, hi = lane >> 4;
  const int tile = blockIdx.x * 4 + w;
  const int row0 = tile * 32;
  if (row0 >= N_NODES) return;
  const int nr = min(32, N_NODES - row0);
  const int g = lane >> 5;               // 0..1
  const int c4 = (lane & 31) << 2;

  // stage x rows -> As (wave-private)
  #pragma unroll
  for (int i = 0; i < 16; ++i) {
    int r = i * 2 + g;
    ushort4 o = make_ushort4(0, 0, 0, 0);
    if (r < nr) {
      if (XF32) {
        float4 v = *(const float4*)((const float*)xg + (size_t)(row0 + r) * 128 + c4);
        o.x = f2bf(v.x); o.y = f2bf(v.y); o.z = f2bf(v.z); o.w = f2bf(v.w);
      } else {
        o = *(const ushort4*)((const u16*)xg + (size_t)(row0 + r) * 128 + c4);
      }
    }
    *(ushort4*)(As + opsw(r, c4)) = o;
  }

  f32x4 qacc[2][8], sacc[2][8];
  acc_zero(qacc); acc_zero(sacc);
  #pragma unroll
  for (int ks = 0; ks < 4; ++ks) {
    const int kb = ks * 32 + hi * 8;
    bf16x8 a0 = *(const bf16x8*)(As + opsw(lr, kb));
    bf16x8 a1 = *(const bf16x8*)(As + opsw(16 + lr, kb));
    #pragma unroll
    for (int nb = 0; nb < 8; ++nb) {
      bf16x8 bq = *(const bf16x8*)(WtQ + (nb * 16 + lr) * 128 + kb);
      bf16x8 bs = *(const bf16x8*)(WtS + (nb * 16 + lr) * 128 + kb);
      qacc[0][nb] = mfma16(a0, bq, qacc[0][nb]);
      qacc[1][nb] = mfma16(a1, bq, qacc[1][nb]);
      sacc[0][nb] = mfma16(a0, bs, sacc[0][nb]);
      sacc[1][nb] = mfma16(a1, bs, sacc[1][nb]);
    }
  }
  acc_to_lds(As, qacc, lane);
  lds_to_global(As, Qo, row0, nr, lane);
  acc_to_lds(As, sacc, lane);
  lds_to_global(As, So, row0, nr, lane);
}

// ---------------- fused edge kernel; per-wave 32-edge tile, no barriers ----------------

template<int XF32>
__global__ __launch_bounds__(256)
void edge_pass(const void* __restrict__ xg, const u16* __restrict__ WtK,
               const u16* __restrict__ WtV, const float* __restrict__ Wa,
               const float* __restrict__ tw, const float* __restrict__ tb,
               const float* __restrict__ dw, const float* __restrict__ db,
               const float* __restrict__ ttab, const float* __restrict__ attr,
               const float* __restrict__ dt, const float* __restrict__ dsv,
               const int* __restrict__ srcA, const int* __restrict__ dstA,
               const int* __restrict__ etA, const int* __restrict__ sortedE,
               const u16* __restrict__ Qb, float* __restrict__ logits,
               u16* __restrict__ Vs)
{
  __shared__ __align__(16) u16 AsAll[4][4160];
  __shared__ int dstShAll[4][32];
  const int t = threadIdx.x;
  const int w = t >> 6, lane = t & 63;
  u16* As = AsAll[w];
  int* dstSh = dstShAll[w];
  const int lr = lane & 15, hi = lane >> 4;
  const int tile = blockIdx.x * 4 + w;
  const int e0 = tile * 32;
  if (e0 >= E_EDGES) return;
  const int ne = min(32, E_EDGES - e0);
  const int g = lane >> 5;
  const int c4 = (lane & 31) << 2;

  float4 tw4 = *(const float4*)(tw + c4);
  float4 tb4 = *(const float4*)(tb + c4);
  float4 dw4 = *(const float4*)(dw + c4);
  float4 db4 = *(const float4*)(db + c4);
  float4 wa4[8];
  #pragma unroll
  for (int a = 0; a < 8; ++a) wa4[a] = *(const float4*)(Wa + a * 128 + c4);

  // stage kv_in = x[src] + attr@Wa + cos(dt*tw+tb) + cos(ds*dw+db) + tt[et]
  #pragma unroll
  for (int i = 0; i < 16; ++i) {
    int r = i * 2 + g;
    ushort4 o = make_ushort4(0, 0, 0, 0);
    if (r < ne) {
      int eid = sortedE[e0 + r];
      if ((lane & 31) == 0) dstSh[r] = dstA[eid];
      int et = etA[eid];
      float dtn = dt[eid] * (1.0f / 24.0f);
      float dss = dsv[eid];
      float4 tt4 = *(const float4*)(ttab + et * 128 + c4);
      float f0 = __cosf(fmaf(dtn, tw4.x, tb4.x)) + __cosf(fmaf(dss, dw4.x, db4.x)) + tt4.x;
      float f1 = __cosf(fmaf(dtn, tw4.y, tb4.y)) + __cosf(fmaf(dss, dw4.y, db4.y)) + tt4.y;
      float f2 = __cosf(fmaf(dtn, tw4.z, tb4.z)) + __cosf(fmaf(dss, dw4.z, db4.z)) + tt4.z;
      float f3 = __cosf(fmaf(dtn, tw4.w, tb4.w)) + __cosf(fmaf(dss, dw4.w, db4.w)) + tt4.w;
      const float* ap = attr + (size_t)eid * 8;
      #pragma unroll
      for (int a = 0; a < 8; ++a) {
        float aa = ap[a];
        f0 = fmaf(aa, wa4[a].x, f0);
        f1 = fmaf(aa, wa4[a].y, f1);
        f2 = fmaf(aa, wa4[a].z, f2);
        f3 = fmaf(aa, wa4[a].w, f3);
      }
      int src = srcA[eid];
      float x0, x1, x2, x3;
      if (XF32) {
        float4 xr = *(const float4*)((const float*)xg + (size_t)src * 128 + c4);
        x0 = xr.x; x1 = xr.y; x2 = xr.z; x3 = xr.w;
      } else {
        ushort4 xr = *(const ushort4*)((const u16*)xg + (size_t)src * 128 + c4);
        x0 = b2f(xr.x); x1 = b2f(xr.y); x2 = b2f(xr.z); x3 = b2f(xr.w);
      }
      o.x = f2bf(x0 + f0);
      o.y = f2bf(x1 + f1);
      o.z = f2bf(x2 + f2);
      o.w = f2bf(x3 + f3);
    } else {
      if ((lane & 31) == 0) dstSh[r] = 0;   // safe Q gather for pad rows
    }
    *(ushort4*)(As + opsw(r, c4)) = o;
  }

  // ---- K GEMM, swapped operands: D[i=n][j=edge]; kacc[eb][nb] ----
  f32x4 kacc[2][8];
  acc_zero(kacc);
  #pragma unroll
  for (int ks = 0; ks < 4; ++ks) {
    const int kb = ks * 32 + hi * 8;
    bf16x8 ef0 = *(const bf16x8*)(As + opsw(lr, kb));        // edge cols 0..15
    bf16x8 ef1 = *(const bf16x8*)(As + opsw(16 + lr, kb));   // edge cols 16..31
    #pragma unroll
    for (int nb = 0; nb < 8; ++nb) {
      bf16x8 af = *(const bf16x8*)(WtK + (nb * 16 + lr) * 128 + kb);
      kacc[0][nb] = mfma16(af, ef0, kacc[0][nb]);
      kacc[1][nb] = mfma16(af, ef1, kacc[1][nb]);
    }
  }

  // logits: lane owns edge el = eb*16+lr; K[el][n = nb*16 + hi*4 + j]
  #pragma unroll
  for (int eb = 0; eb < 2; ++eb) {
    int el = eb * 16 + lr;
    int dstn = dstSh[el];
    float hs[4] = {0.f, 0.f, 0.f, 0.f};
    #pragma unroll
    for (int nb = 0; nb < 8; ++nb) {
      ushort4 q = *(const ushort4*)(Qb + (size_t)dstn * 128 + nb * 16 + hi * 4);
      hs[nb >> 1] += b2f(q.x) * kacc[eb][nb][0] + b2f(q.y) * kacc[eb][nb][1]
                   + b2f(q.z) * kacc[eb][nb][2] + b2f(q.w) * kacc[eb][nb][3];
    }
    #pragma unroll
    for (int h = 0; h < 4; ++h) {
      hs[h] += __shfl_xor(hs[h], 16, 64);
      hs[h] += __shfl_xor(hs[h], 32, 64);
      hs[h] *= 0.17677669529663687f;                 // 32^-0.5
      hs[h] = (hs[h] >= 0.f) ? hs[h] : 0.2f * hs[h]; // leaky relu
    }
    if (lane < 16 && el < ne)
      *(float4*)(logits + (size_t)(e0 + el) * 4) = make_float4(hs[0], hs[1], hs[2], hs[3]);
  }

  // ---- V GEMM, normal orientation: D[i=edge][j=n] ----
  f32x4 vacc[2][8];
  acc_zero(vacc);
  #pragma unroll
  for (int ks = 0; ks < 4; ++ks) {
    const int kb = ks * 32 + hi * 8;
    bf16x8 af0 = *(const bf16x8*)(As + opsw(lr, kb));
    bf16x8 af1 = *(const bf16x8*)(As + opsw(16 + lr, kb));
    #pragma unroll
    for (int nb = 0; nb < 8; ++nb) {
      bf16x8 bf = *(const bf16x8*)(WtV + (nb * 16 + lr) * 128 + kb);
      vacc[0][nb] = mfma16(af0, bf, vacc[0][nb]);
      vacc[1][nb] = mfma16(af1, bf, vacc[1][nb]);
    }
  }
  acc_to_lds(As, vacc, lane);   // same-wave DS ops are ordered; reuse As as C tile
  lds_to_global(As, Vs, e0, ne, lane);
}

// ---------------- per-node softmax + aggregate + combine + stats ----------------
__global__ __launch_bounds__(256)
void node_agg(const u16* __restrict__ Vs, const float* __restrict__ logits,
              const int* __restrict__ rowptr, const u16* __restrict__ S,
              const float* __restrict__ betaP, float* __restrict__ pre,
              float* __restrict__ colsum, float* __restrict__ colsumsq)
{
  __shared__ float red[1024];
  const int t = threadIdx.x;
  const int g = t >> 5;
  const int lane = t & 31;
  const int d0 = lane * 4;
  const int h = lane >> 3;
  const float beta = *betaP;
  const float omb = 1.f - beta;
  float s4[4] = {0.f, 0.f, 0.f, 0.f};
  float q4[4] = {0.f, 0.f, 0.f, 0.f};
  for (int rep = 0; rep < 16; ++rep) {
    int n = blockIdx.x * 128 + rep * 8 + g;
    if (n < N_NODES) {
      int rs = rowptr[n], re = rowptr[n + 1];
      float m = -1e30f;
      for (int i = rs; i < re; ++i)
        m = fmaxf(m, logits[(size_t)i * 4 + h]);
      float den = 0.f;
      float a0 = 0.f, a1 = 0.f, a2 = 0.f, a3 = 0.f;
      for (int i = rs; i < re; ++i) {
        float wgt = __expf(logits[(size_t)i * 4 + h] - m);
        den += wgt;
        ushort4 v = *(const ushort4*)(Vs + (size_t)i * 128 + d0);
        a0 = fmaf(wgt, b2f(v.x), a0);
        a1 = fmaf(wgt, b2f(v.y), a1);
        a2 = fmaf(wgt, b2f(v.z), a2);
        a3 = fmaf(wgt, b2f(v.w), a3);
      }
      float inv = (den > 0.f) ? (omb / den) : 0.f;
      ushort4 sv = *(const ushort4*)(S + (size_t)n * 128 + d0);
      float p0 = fmaf(beta, b2f(sv.x), a0 * inv);
      float p1 = fmaf(beta, b2f(sv.y), a1 * inv);
      float p2 = fmaf(beta, b2f(sv.z), a2 * inv);
      float p3 = fmaf(beta, b2f(sv.w), a3 * inv);
      *(float4*)(pre + (size_t)n * 128 + d0) = make_float4(p0, p1, p2, p3);
      s4[0] += p0; s4[1] += p1; s4[2] += p2; s4[3] += p3;
      q4[0] += p0 * p0; q4[1] += p1 * p1; q4[2] += p2 * p2; q4[3] += p3 * p3;
    }
  }
  *(float4*)(&red[g * 128 + d0]) = make_float4(s4[0], s4[1], s4[2], s4[3]);
  __syncthreads();
  if (t < 128) {
    float tot = 0.f;
    #pragma unroll
    for (int gg = 0; gg < 8; ++gg) tot += red[gg * 128 + t];
    atomicAdd(&colsum[t], tot);
  }
  __syncthreads();
  *(float4*)(&red[g * 128 + d0]) = make_float4(q4[0], q4[1], q4[2], q4[3]);
  __syncthreads();
  if (t < 128) {
    float tot = 0.f;
    #pragma unroll
    for (int gg = 0; gg < 8; ++gg) tot += red[gg * 128 + t];
    atomicAdd(&colsumsq[t], tot);
  }
}

// ---------------- BatchNorm(train stats) + ReLU ----------------
template<int LAST>
__global__ __launch_bounds__(256)
void bn_apply(const float* __restrict__ pre, const float* __restrict__ colsum,
              const float* __restrict__ colsumsq, const float* __restrict__ gamma,
              const float* __restrict__ bvec, u16* __restrict__ outbf,
              float* __restrict__ outf)
{
  const int idx = blockIdx.x * 256 + threadIdx.x;
  const int n = idx >> 5;
  const int d0 = (idx & 31) * 4;
  const float invN = 1.f / 150000.f;
  float4 p = *(const float4*)(pre + (size_t)n * 128 + d0);
  float4 cs = *(const float4*)(colsum + d0);
  float4 cq = *(const float4*)(colsumsq + d0);
  float4 gm = *(const float4*)(gamma + d0);
  float4 bv = *(const float4*)(bvec + d0);
  float mu, var, y;
  mu = cs.x * invN; var = cq.x * invN - mu * mu;
  y = (p.x - mu) * rsqrtf(var + 1e-5f) * gm.x + bv.x; p.x = fmaxf(y, 0.f);
  mu = cs.y * invN; var = cq.y * invN - mu * mu;
  y = (p.y - mu) * rsqrtf(var + 1e-5f) * gm.y + bv.y; p.y = fmaxf(y, 0.f);
  mu = cs.z * invN; var = cq.z * invN - mu * mu;
  y = (p.z - mu) * rsqrtf(var + 1e-5f) * gm.z + bv.z; p.z = fmaxf(y, 0.f);
  mu = cs.w * invN; var = cq.w * invN - mu * mu;
  y = (p.w - mu) * rsqrtf(var + 1e-5f) * gm.w + bv.w; p.w = fmaxf(y, 0.f);
  if (LAST) {
    *(float4*)(outf + (size_t)n * 128 + d0) = p;
  } else {
    ushort4 o;
    o.x = f2bf(p.x); o.y = f2bf(p.y); o.z = f2bf(p.z); o.w = f2bf(p.w);
    *(ushort4*)(outbf + (size_t)n * 128 + d0) = o;
  }
}

extern "C" void kernel_launch(void* const* d_in, const int* in_sizes, int n_in,
                              void* d_out, int out_size, void* d_ws, size_t ws_size,
                              hipStream_t stream)
{
  const float* x0    = (const float*)d_in[0];
  const float* Wq    = (const float*)d_in[1];
  const float* Wk    = (const float*)d_in[2];
  const float* Wv    = (const float*)d_in[3];
  const float* Wsk   = (const float*)d_in[4];
  const float* Wa    = (const float*)d_in[5];
  const float* tw    = (const float*)d_in[6];
  const float* tb    = (const float*)d_in[7];
  const float* dw    = (const float*)d_in[8];
  const float* db    = (const float*)d_in[9];
  const float* ttab  = (const float*)d_in[10];
  const float* gam   = (const float*)d_in[11];
  const float* bet   = (const float*)d_in[12];
  const float* betaP = (const float*)d_in[13];
  const float* attr  = (const float*)d_in[14];
  const float* dt    = (const float*)d_in[15];
  const float* dsv   = (const float*)d_in[16];
  const int*   eidx  = (const int*)d_in[17];
  const int*   etyp  = (const int*)d_in[18];

  // workspace ~207 MB
  char* p = (char*)d_ws;
  u16* xbf  = (u16*)p;       p += 38400000;          // [N,128] bf16
  u16* Q    = (u16*)p;       p += 38400000;          // [N,128] bf16
  u16* S    = (u16*)p;       p += 38400000;          // [N,128] bf16
  u16* Vs   = (u16*)p;       p += 76800000;          // [E,128] bf16 dst-sorted
  float* logits = (float*)p; p += 4800000;           // [E,4] f32 dst-sorted
  int* rowptr = (int*)p;     p += 4 * L_CNT * 4;
  int* tmp    = (int*)p;     p += 4 * L_CNT * 4;
  int* sorted = (int*)p;     p += 4 * E_EDGES * 4;
  int* bsum   = (int*)p;     p += 4 * 128 * 4;
  float* colsum   = (float*)p; p += 512;
  float* colsumsq = (float*)p; p += 512;
  u16* Wt = (u16*)p;         p += 16 * 16384 * 2;    // 16 transposed bf16 weights

  float* pre = (float*)d_out;   // [N,128] f32 scratch (final bn overwrites)

  // weight transpose + CSR build
  k_wt<<<16, 256, 0, stream>>>(Wq, Wk, Wv, Wsk, Wt);
  hipMemsetAsync(tmp, 0, 4 * L_CNT * 4, stream);
  k_hist<<<dim3(1172, 4), 256, 0, stream>>>(eidx, tmp);
  k_scan1<<<dim3(74, 4), 256, 0, stream>>>(tmp, rowptr, bsum);
  k_scan2<<<4, 128, 0, stream>>>(bsum);
  k_scan3<<<dim3(592, 4), 256, 0, stream>>>(rowptr, tmp, bsum);
  k_scatter<<<dim3(1172, 4), 256, 0, stream>>>(eidx, tmp, sorted);

  for (int l = 0; l < 4; ++l) {
    const int* srcA = eidx + (size_t)l * 600000;
    const int* dstA = srcA + 300000;
    const int* sortedE = sorted + (size_t)l * E_EDGES;
    const int* rpl = rowptr + (size_t)l * L_CNT;
    const u16* WtQl = Wt + (size_t)l * 16384;
    const u16* WtKl = Wt + (size_t)(4 + l) * 16384;
    const u16* WtVl = Wt + (size_t)(8 + l) * 16384;
    const u16* WtSl = Wt + (size_t)(12 + l) * 16384;
    const float* Wal = Wa + (size_t)l * 1024;
    const float* attrl = attr + (size_t)l * 2400000;
    const float* dtl = dt + (size_t)l * 300000;
    const float* dsl = dsv + (size_t)l * 300000;
    const int* etl = etyp + (size_t)l * 300000;

    hipMemsetAsync(colsum, 0, 1024, stream);

    if (l == 0) {
      gemm_qs<1><<<1172, 256, 0, stream>>>((const void*)x0, WtQl, WtSl, Q, S);
      edge_pass<1><<<2344, 256, 0, stream>>>(
          (const void*)x0, WtKl, WtVl, Wal, tw, tb, dw, db, ttab, attrl,
          dtl, dsl, srcA, dstA, etl, sortedE, Q, logits, Vs);
    } else {
      gemm_qs<0><<<1172, 256, 0, stream>>>((const void*)xbf, WtQl, WtSl, Q, S);
      edge_pass<0><<<2344, 256, 0, stream>>>(
          (const void*)xbf, WtKl, WtVl, Wal, tw, tb, dw, db, ttab, attrl,
          dtl, dsl, srcA, dstA, etl, sortedE, Q, logits, Vs);
    }

    node_agg<<<1172, 256, 0, stream>>>(Vs, logits, rpl, S, betaP + l,
                                       pre, colsum, colsumsq);

    if (l < 3)
      bn_apply<0><<<18750, 256, 0, stream>>>(pre, colsum, colsumsq,
                                             gam + (size_t)l * 128,
                                             bet + (size_t)l * 128, xbf, nullptr);
    else
      bn_apply<1><<<18750, 256, 0, stream>>>(pre, colsum, colsumsq,
                                             gam + (size_t)l * 128,
                                             bet + (size_t)l * 128,
                                             nullptr, (float*)d_out);
  }
}